// Round 2
// baseline (2847.460 us; speedup 1.0000x reference)
//
#include <hip/hip_runtime.h>
#include <hip/hip_bf16.h>

typedef __hip_bfloat16 bf16;

static __device__ __forceinline__ float b2f(bf16 x) { return __bfloat162float(x); }

// dtype-dispatched load/store: f32=1 -> buffer is float32, f32=0 -> bfloat16.
static __device__ __forceinline__ float ldf(const void* p, size_t i, int f32) {
    return f32 ? ((const float*)p)[i] : b2f(((const bf16*)p)[i]);
}
static __device__ __forceinline__ void stf(void* p, size_t i, int f32, float v) {
    if (f32) ((float*)p)[i] = v;
    else     ((bf16*)p)[i] = __float2bfloat16(v);
}

// ---------------- dtype detector ----------------
// Inspect a_attn (128 elems ~ N(0,0.01)) as raw u16 words. bf16 data: every
// word has a plausible exponent. fp32 data: even (low-half) words have
// uniform-random exponent bits -> ~55/128 implausible.
__global__ void detect_kernel(const unsigned short* __restrict__ a, int* __restrict__ flag)
{
    __shared__ int cnt;
    if (threadIdx.x == 0) cnt = 0;
    __syncthreads();
    unsigned e = (a[threadIdx.x] >> 7) & 0xFF;
    if (e < 100 || e > 133) atomicAdd(&cnt, 1);
    __syncthreads();
    if (threadIdx.x == 0) *flag = (cnt >= 16) ? 1 : 0;   // 1 => float32 tensors
}

// ---------------- node prep: v projection + per-node score scalars ----------------
__global__ __launch_bounds__(256) void node_prep_kernel(
    const void* __restrict__ x, const void* __restrict__ Wq,
    const void* __restrict__ Wk, const void* __restrict__ Wv,
    const void* __restrict__ emb, const void* __restrict__ a_attn,
    const int* __restrict__ flagp,
    float* __restrict__ v_out, float* __restrict__ sq_out, float* __restrict__ sk_out,
    int n_nodes)
{
    const int f32 = *flagp;
    __shared__ float Wq_s[64 * 64], Wk_s[64 * 64], Wv_s[64 * 64];
    __shared__ float emb_s[64], a_s[64];
    for (int i = threadIdx.x; i < 64 * 64; i += 256) {
        Wq_s[i] = ldf(Wq, i, f32); Wk_s[i] = ldf(Wk, i, f32); Wv_s[i] = ldf(Wv, i, f32);
    }
    if (threadIdx.x < 64) {
        emb_s[threadIdx.x] = ldf(emb, threadIdx.x, f32);
        a_s[threadIdx.x]   = ldf(a_attn, threadIdx.x, f32);
    }
    __syncthreads();

    const int lane   = threadIdx.x & 63;
    const int wave   = (blockIdx.x * blockDim.x + threadIdx.x) >> 6;
    const int nwaves = (gridDim.x * blockDim.x) >> 6;

    for (int n = wave; n < n_nodes; n += nwaves) {
        float xv = ldf(x, (size_t)n * 64 + lane, f32);
        float q = 0.f, k = 0.f, v = 0.f;
        #pragma unroll
        for (int c = 0; c < 64; ++c) {
            float xc = __shfl(xv, c, 64);
            q += xc * Wq_s[c * 64 + lane];
            k += xc * Wk_s[c * 64 + lane];
            v += xc * Wv_s[c * 64 + lane];
        }
        v_out[(size_t)n * 64 + lane] = v;
        float tq = tanhf(q + emb_s[lane]) * a_s[lane & 31];
        float tk = tanhf(k + emb_s[lane]) * a_s[32 + (lane & 31)];
        #pragma unroll
        for (int off = 16; off; off >>= 1) {
            tq += __shfl_xor(tq, off, 32);
            tk += __shfl_xor(tk, off, 32);
        }
        if ((lane & 31) == 0) {
            int h = lane >> 5;
            sq_out[n * 2 + h] = tq;
            sk_out[n * 2 + h] = tk;
        }
    }
}

// ---------------- relation constants ----------------
__global__ void rel_const_kernel(const void* __restrict__ rel1, const void* __restrict__ rel2,
                                 const void* __restrict__ a_attn, const int* __restrict__ flagp,
                                 float* __restrict__ cvals)
{
    const int f32 = *flagp;
    int t = threadIdx.x;             // 128 threads: wave0 -> rel1, wave1 -> rel2
    const void* r = (t < 64) ? rel1 : rel2;
    int l = t & 63;
    float v = tanhf(ldf(r, l, f32)) * ldf(a_attn, 64 + (l & 31), f32);
    #pragma unroll
    for (int off = 16; off; off >>= 1) v += __shfl_xor(v, off, 32);
    if ((l & 31) == 0) cvals[(t >> 6) * 2 + (l >> 5)] = v;
}

// ---------------- edge scores: accumulate softmax denominator only ----------------
__global__ __launch_bounds__(256) void edge_score_kernel(
    const void* __restrict__ ea, const void* __restrict__ We,
    const int* __restrict__ row, const int* __restrict__ col,
    const float* __restrict__ sq_dst, const float* __restrict__ sk_src,
    const float* __restrict__ cvals, const void* __restrict__ a_attn,
    const int* __restrict__ flagp,
    float* __restrict__ s_out, int num_e)
{
    const int f32 = *flagp;
    __shared__ float We_s[16 * 64];
    __shared__ float a3_s[32];
    __shared__ float c_s[2];
    for (int i = threadIdx.x; i < 16 * 64; i += 256) We_s[i] = ldf(We, i, f32);
    if (threadIdx.x < 32) a3_s[threadIdx.x] = ldf(a_attn, 96 + threadIdx.x, f32);
    if (threadIdx.x < 2)  c_s[threadIdx.x]  = cvals[threadIdx.x];
    __syncthreads();

    const int lane   = threadIdx.x & 63;
    const int h      = lane >> 5;
    const int wave   = (blockIdx.x * blockDim.x + threadIdx.x) >> 6;
    const int nwaves = (gridDim.x * blockDim.x) >> 6;

    for (int e = wave; e < num_e; e += nwaves) {
        float eav = (lane < 16) ? ldf(ea, (size_t)e * 16 + lane, f32) : 0.f;
        float ebl = 0.f;
        #pragma unroll
        for (int c = 0; c < 16; ++c) {
            float ec = __shfl(eav, c, 64);
            ebl += ec * We_s[c * 64 + lane];
        }
        float t = tanhf(ebl) * a3_s[lane & 31];
        #pragma unroll
        for (int off = 16; off; off >>= 1) t += __shfl_xor(t, off, 32);
        // butterfly leaves every lane holding the half-wave sum
        int d = col[e], s = row[e];
        float score = t + sq_dst[d * 2 + h] + sk_src[s * 2 + h] + c_s[h];
        score = fminf(30.f, fmaxf(-30.f, score));   // never active for sane data
        float ex = __expf(score);
        if ((lane & 31) == 0) atomicAdd(&s_out[d * 2 + h], ex);
    }
}

// ---------------- edge aggregation: agg[col] += w * (v[row] + rel + eb) ----------------
__global__ __launch_bounds__(256) void edge_agg_kernel(
    const void* __restrict__ ea, const void* __restrict__ We,
    const int* __restrict__ row, const int* __restrict__ col,
    const float* __restrict__ v_src, const void* __restrict__ rel_emb,
    const float* __restrict__ sq_dst, const float* __restrict__ sk_src,
    const float* __restrict__ cvals, const void* __restrict__ a_attn,
    const int* __restrict__ flagp,
    const float* __restrict__ s_in, float* __restrict__ agg, int num_e)
{
    const int f32 = *flagp;
    __shared__ float We_s[16 * 64];
    __shared__ float rel_s[64];
    __shared__ float a3_s[32];
    __shared__ float c_s[2];
    for (int i = threadIdx.x; i < 16 * 64; i += 256) We_s[i] = ldf(We, i, f32);
    if (threadIdx.x < 64) rel_s[threadIdx.x] = ldf(rel_emb, threadIdx.x, f32);
    if (threadIdx.x < 32) a3_s[threadIdx.x] = ldf(a_attn, 96 + threadIdx.x, f32);
    if (threadIdx.x < 2)  c_s[threadIdx.x]  = cvals[threadIdx.x];
    __syncthreads();

    const int lane   = threadIdx.x & 63;
    const int h      = lane >> 5;
    const int wave   = (blockIdx.x * blockDim.x + threadIdx.x) >> 6;
    const int nwaves = (gridDim.x * blockDim.x) >> 6;

    for (int e = wave; e < num_e; e += nwaves) {
        int r = row[e], d = col[e];
        float eav = (lane < 16) ? ldf(ea, (size_t)e * 16 + lane, f32) : 0.f;
        float ebl = 0.f;
        #pragma unroll
        for (int c = 0; c < 16; ++c) {
            float ec = __shfl(eav, c, 64);
            ebl += ec * We_s[c * 64 + lane];
        }
        float t = tanhf(ebl) * a3_s[lane & 31];
        #pragma unroll
        for (int off = 16; off; off >>= 1) t += __shfl_xor(t, off, 32);
        float score = t + sq_dst[d * 2 + h] + sk_src[r * 2 + h] + c_s[h];
        score = fminf(30.f, fmaxf(-30.f, score));
        float w = __expf(score) / s_in[d * 2 + h];
        float msg = v_src[(size_t)r * 64 + lane] + rel_s[lane] + ebl;
        atomicAdd(&agg[(size_t)d * 64 + lane], w * msg);
    }
}

// ---------------- final: out = agg @ Wo + bo + x @ Wr ----------------
// out_elem_off lets the host express the type-b offset in ELEMENTS so the
// byte offset adapts to the detected dtype on device.
__global__ __launch_bounds__(256) void final_kernel(
    const float* __restrict__ agg, const void* __restrict__ x,
    const void* __restrict__ Wo, const void* __restrict__ bo,
    const void* __restrict__ Wr, const int* __restrict__ flagp,
    void* __restrict__ out, size_t out_elem_off, int n_nodes)
{
    const int f32 = *flagp;
    __shared__ float Wo_s[64 * 32], Wr_s[64 * 32];
    __shared__ float bo_s[32];
    for (int i = threadIdx.x; i < 64 * 32; i += 256) { Wo_s[i] = ldf(Wo, i, f32); Wr_s[i] = ldf(Wr, i, f32); }
    if (threadIdx.x < 32) bo_s[threadIdx.x] = ldf(bo, threadIdx.x, f32);
    __syncthreads();

    const int lane   = threadIdx.x & 63;
    const int j      = lane & 31;
    const int half   = lane >> 5;
    const int wave   = (blockIdx.x * blockDim.x + threadIdx.x) >> 6;
    const int nwaves = (gridDim.x * blockDim.x) >> 6;
    const int pairs  = (n_nodes + 1) >> 1;

    for (int p = wave; p < pairs; p += nwaves) {
        int n = p * 2 + half;
        bool valid = (n < n_nodes);
        int nn = valid ? n : (n_nodes - 1);
        float a0 = agg[(size_t)nn * 64 + j];
        float a1 = agg[(size_t)nn * 64 + 32 + j];
        float x0 = ldf(x, (size_t)nn * 64 + j, f32);
        float x1 = ldf(x, (size_t)nn * 64 + 32 + j, f32);
        float acc = bo_s[j];
        #pragma unroll
        for (int c = 0; c < 32; ++c) {
            float ac0 = __shfl(a0, c, 32);
            float ac1 = __shfl(a1, c, 32);
            float xc0 = __shfl(x0, c, 32);
            float xc1 = __shfl(x1, c, 32);
            acc += ac0 * Wo_s[c * 32 + j] + ac1 * Wo_s[(32 + c) * 32 + j]
                 + xc0 * Wr_s[c * 32 + j] + xc1 * Wr_s[(32 + c) * 32 + j];
        }
        if (valid) stf(out, out_elem_off + (size_t)n * 32 + j, f32, acc);
    }
}

extern "C" void kernel_launch(void* const* d_in, const int* in_sizes, int n_in,
                              void* d_out, int out_size, void* d_ws, size_t ws_size,
                              hipStream_t stream)
{
    const void* x_a   = d_in[0];
    const void* x_b   = d_in[1];
    const void* ea1   = d_in[2];
    const void* ea2   = d_in[3];
    const void* Wq_a  = d_in[4];
    const void* Wk_a  = d_in[5];
    const void* Wv_a  = d_in[6];
    const void* Wq_b  = d_in[7];
    const void* Wk_b  = d_in[8];
    const void* Wv_b  = d_in[9];
    const void* emb_a = d_in[10];
    const void* emb_b = d_in[11];
    const void* rel1  = d_in[12];
    const void* rel2  = d_in[13];
    const void* We    = d_in[14];
    const void* a_at  = d_in[15];
    const void* Wo_a  = d_in[16];
    const void* bo_a  = d_in[17];
    const void* Wo_b  = d_in[18];
    const void* bo_b  = d_in[19];
    const void* Wr_a  = d_in[20];
    const void* Wr_b  = d_in[21];
    const int*  row1  = (const int*)d_in[22];
    const int*  col1  = (const int*)d_in[23];
    const int*  row2  = (const int*)d_in[24];
    const int*  col2  = (const int*)d_in[25];

    const int N = in_sizes[0] / 64;   // nodes per type
    const int E = in_sizes[22];       // edges per relation

    // ---- workspace layout (fp32) ----
    float* ws = (float*)d_ws;
    size_t off = 0;
    int*   flag = (int*)ws; off += 64;             // 256-B header
    float* v_a  = ws + off; off += (size_t)N * 64;
    float* v_b  = ws + off; off += (size_t)N * 64;
    float* sq_a = ws + off; off += (size_t)N * 2;
    float* sk_a = ws + off; off += (size_t)N * 2;
    float* sq_b = ws + off; off += (size_t)N * 2;
    float* sk_b = ws + off; off += (size_t)N * 2;
    float* cvals = ws + off; off += 4;
    // zero-initialized region (contiguous, single memset)
    float* zero_base = ws + off;
    float* s1    = ws + off; off += (size_t)N * 2;
    float* s2    = ws + off; off += (size_t)N * 2;
    float* agg_a = ws + off; off += (size_t)N * 64;
    float* agg_b = ws + off; off += (size_t)N * 64;
    size_t zero_bytes = (size_t)(N * 2 * 2 + N * 64 * 2) * sizeof(float);

    const int node_blocks = (N * 64 + 255) / 256;                 // wave-per-node
    const int edge_blocks = (int)(((size_t)E * 64 + 255) / 256);  // wave-per-edge
    const int fin_blocks  = ((((N + 1) / 2) * 64) + 255) / 256;   // wave-per-2-nodes

    detect_kernel<<<1, 128, 0, stream>>>((const unsigned short*)a_at, flag);
    hipMemsetAsync(zero_base, 0, zero_bytes, stream);

    node_prep_kernel<<<node_blocks, 256, 0, stream>>>(x_a, Wq_a, Wk_a, Wv_a, emb_a, a_at, flag, v_a, sq_a, sk_a, N);
    node_prep_kernel<<<node_blocks, 256, 0, stream>>>(x_b, Wq_b, Wk_b, Wv_b, emb_b, a_at, flag, v_b, sq_b, sk_b, N);
    rel_const_kernel<<<1, 128, 0, stream>>>(rel1, rel2, a_at, flag, cvals);

    // relation 1: a -> b ; relation 2: b -> a
    edge_score_kernel<<<edge_blocks, 256, 0, stream>>>(ea1, We, row1, col1, sq_b, sk_a, cvals + 0, a_at, flag, s1, E);
    edge_score_kernel<<<edge_blocks, 256, 0, stream>>>(ea2, We, row2, col2, sq_a, sk_b, cvals + 2, a_at, flag, s2, E);

    edge_agg_kernel<<<edge_blocks, 256, 0, stream>>>(ea1, We, row1, col1, v_a, rel1, sq_b, sk_a, cvals + 0, a_at, flag, s1, agg_b, E);
    edge_agg_kernel<<<edge_blocks, 256, 0, stream>>>(ea2, We, row2, col2, v_b, rel2, sq_a, sk_b, cvals + 2, a_at, flag, s2, agg_a, E);

    final_kernel<<<fin_blocks, 256, 0, stream>>>(agg_a, x_a, Wo_a, bo_a, Wr_a, flag, d_out, 0, N);
    final_kernel<<<fin_blocks, 256, 0, stream>>>(agg_b, x_b, Wo_b, bo_b, Wr_b, flag, d_out, (size_t)N * 32, N);
}

// Round 3
// 2662.591 us; speedup vs baseline: 1.0694x; 1.0694x over previous
//
#include <hip/hip_runtime.h>
#include <hip/hip_bf16.h>

typedef __hip_bfloat16 bf16;

static __device__ __forceinline__ float b2f(bf16 x) { return __bfloat162float(x); }

// dtype-dispatched load/store: f32=1 -> buffer is float32, f32=0 -> bfloat16.
static __device__ __forceinline__ float ldf(const void* p, size_t i, int f32) {
    return f32 ? ((const float*)p)[i] : b2f(((const bf16*)p)[i]);
}
static __device__ __forceinline__ void stf(void* p, size_t i, int f32, float v) {
    if (f32) ((float*)p)[i] = v;
    else     ((bf16*)p)[i] = __float2bfloat16(v);
}

// fast tanh: 1 - 2/(e^2x + 1).  exp->inf => 1, exp->0 => -1.  ~1e-7 rel err.
static __device__ __forceinline__ float fast_tanh(float x) {
    float t = __expf(2.f * x);
    return 1.f - 2.f * __builtin_amdgcn_rcpf(t + 1.f);
}

// load 16 edge-attr channels of edge e into registers (either dtype)
static __device__ __forceinline__ void load_ea16(const void* ea, size_t e, int f32, float* er) {
    if (f32) {
        const float4* p = (const float4*)((const float*)ea + e * 16);
        #pragma unroll
        for (int q = 0; q < 4; ++q) {
            float4 v = p[q];
            er[4*q] = v.x; er[4*q+1] = v.y; er[4*q+2] = v.z; er[4*q+3] = v.w;
        }
    } else {
        const uint4* p = (const uint4*)((const bf16*)ea + e * 16);
        #pragma unroll
        for (int q = 0; q < 2; ++q) {
            uint4 u = p[q];
            unsigned w0 = u.x, w1 = u.y, w2 = u.z, w3 = u.w;
            er[8*q+0] = __uint_as_float(w0 << 16);
            er[8*q+1] = __uint_as_float(w0 & 0xffff0000u);
            er[8*q+2] = __uint_as_float(w1 << 16);
            er[8*q+3] = __uint_as_float(w1 & 0xffff0000u);
            er[8*q+4] = __uint_as_float(w2 << 16);
            er[8*q+5] = __uint_as_float(w2 & 0xffff0000u);
            er[8*q+6] = __uint_as_float(w3 << 16);
            er[8*q+7] = __uint_as_float(w3 & 0xffff0000u);
        }
    }
}

// ---------------- dtype detector ----------------
__global__ void detect_kernel(const unsigned short* __restrict__ a, int* __restrict__ flag)
{
    __shared__ int cnt;
    if (threadIdx.x == 0) cnt = 0;
    __syncthreads();
    unsigned e = (a[threadIdx.x] >> 7) & 0xFF;
    if (e < 100 || e > 133) atomicAdd(&cnt, 1);
    __syncthreads();
    if (threadIdx.x == 0) *flag = (cnt >= 16) ? 1 : 0;   // 1 => float32 tensors
}

// ---------------- node prep: v projection + per-node score scalars ----------------
__global__ __launch_bounds__(256) void node_prep_kernel(
    const void* __restrict__ x, const void* __restrict__ Wq,
    const void* __restrict__ Wk, const void* __restrict__ Wv,
    const void* __restrict__ emb, const void* __restrict__ a_attn,
    const int* __restrict__ flagp,
    float* __restrict__ v_out, float* __restrict__ sq_out, float* __restrict__ sk_out,
    int n_nodes)
{
    const int f32 = *flagp;
    __shared__ float Wq_s[64 * 64], Wk_s[64 * 64], Wv_s[64 * 64];
    __shared__ float emb_s[64], a_s[64];
    for (int i = threadIdx.x; i < 64 * 64; i += 256) {
        Wq_s[i] = ldf(Wq, i, f32); Wk_s[i] = ldf(Wk, i, f32); Wv_s[i] = ldf(Wv, i, f32);
    }
    if (threadIdx.x < 64) {
        emb_s[threadIdx.x] = ldf(emb, threadIdx.x, f32);
        a_s[threadIdx.x]   = ldf(a_attn, threadIdx.x, f32);
    }
    __syncthreads();

    const int lane   = threadIdx.x & 63;
    const int wave   = (blockIdx.x * blockDim.x + threadIdx.x) >> 6;
    const int nwaves = (gridDim.x * blockDim.x) >> 6;

    for (int n = wave; n < n_nodes; n += nwaves) {
        float xv = ldf(x, (size_t)n * 64 + lane, f32);
        float q = 0.f, k = 0.f, v = 0.f;
        #pragma unroll
        for (int c = 0; c < 64; ++c) {
            float xc = __shfl(xv, c, 64);
            q += xc * Wq_s[c * 64 + lane];
            k += xc * Wk_s[c * 64 + lane];
            v += xc * Wv_s[c * 64 + lane];
        }
        v_out[(size_t)n * 64 + lane] = v;
        float tq = fast_tanh(q + emb_s[lane]) * a_s[lane & 31];
        float tk = fast_tanh(k + emb_s[lane]) * a_s[32 + (lane & 31)];
        #pragma unroll
        for (int off = 16; off; off >>= 1) {
            tq += __shfl_xor(tq, off, 32);
            tk += __shfl_xor(tk, off, 32);
        }
        if ((lane & 31) == 0) {
            int h = lane >> 5;
            sq_out[n * 2 + h] = tq;
            sk_out[n * 2 + h] = tk;
        }
    }
}

// ---------------- relation constants ----------------
__global__ void rel_const_kernel(const void* __restrict__ rel1, const void* __restrict__ rel2,
                                 const void* __restrict__ a_attn, const int* __restrict__ flagp,
                                 float* __restrict__ cvals)
{
    const int f32 = *flagp;
    int t = threadIdx.x;             // 128 threads: wave0 -> rel1, wave1 -> rel2
    const void* r = (t < 64) ? rel1 : rel2;
    int l = t & 63;
    float v = tanhf(ldf(r, l, f32)) * ldf(a_attn, 64 + (l & 31), f32);
    #pragma unroll
    for (int off = 16; off; off >>= 1) v += __shfl_xor(v, off, 32);
    if ((l & 31) == 0) cvals[(t >> 6) * 2 + (l >> 5)] = v;
}

// ---------------- edge scores: thread per 2 edges, write ex + denominators ----------------
__global__ __launch_bounds__(256) void edge_score_kernel(
    const void* __restrict__ ea, const void* __restrict__ We,
    const int* __restrict__ row, const int* __restrict__ col,
    const float* __restrict__ sq_dst, const float* __restrict__ sk_src,
    const float* __restrict__ cvals, const void* __restrict__ a_attn,
    const int* __restrict__ flagp,
    float* __restrict__ ex_out, float* __restrict__ s_out, int num_e)
{
    const int f32 = *flagp;
    __shared__ float We_s[16 * 64];
    __shared__ float a3_s[32];
    __shared__ float c_s[2];
    for (int i = threadIdx.x; i < 16 * 64; i += 256) We_s[i] = ldf(We, i, f32);
    if (threadIdx.x < 32) a3_s[threadIdx.x] = ldf(a_attn, 96 + threadIdx.x, f32);
    if (threadIdx.x < 2)  c_s[threadIdx.x]  = cvals[threadIdx.x];
    __syncthreads();

    const int base = blockIdx.x * 512 + threadIdx.x;
    const int e0 = base;         // edge for register set 0
    const int e1 = base + 256;   // edge for register set 1
    const bool v0 = (e0 < num_e), v1 = (e1 < num_e);
    if (!v0) return;

    float er0[16], er1[16];
    load_ea16(ea, (size_t)e0, f32, er0);
    if (v1) load_ea16(ea, (size_t)e1, f32, er1);
    else {
        #pragma unroll
        for (int c = 0; c < 16; ++c) er1[c] = 0.f;
    }

    float acc00 = 0.f, acc01 = 0.f, acc10 = 0.f, acc11 = 0.f;
    #pragma unroll
    for (int jb = 0; jb < 64; jb += 8) {
        float t0[8], t1[8];
        #pragma unroll
        for (int jj = 0; jj < 8; ++jj) { t0[jj] = 0.f; t1[jj] = 0.f; }
        #pragma unroll
        for (int c = 0; c < 16; ++c) {
            #pragma unroll
            for (int jj = 0; jj < 8; ++jj) {
                float w = We_s[c * 64 + jb + jj];   // adjacent -> ds_read_b128
                t0[jj] += er0[c] * w;
                t1[jj] += er1[c] * w;
            }
        }
        #pragma unroll
        for (int jj = 0; jj < 8; ++jj) {
            float a  = a3_s[(jb + jj) & 31];
            float th0 = fast_tanh(t0[jj]) * a;
            float th1 = fast_tanh(t1[jj]) * a;
            if (jb + jj < 32) { acc00 += th0; acc10 += th1; }
            else              { acc01 += th0; acc11 += th1; }
        }
    }

    {   // edge e0
        int d = col[e0], s = row[e0];
        float s0 = acc00 + sq_dst[d * 2 + 0] + sk_src[s * 2 + 0] + c_s[0];
        float s1 = acc01 + sq_dst[d * 2 + 1] + sk_src[s * 2 + 1] + c_s[1];
        s0 = fminf(30.f, fmaxf(-30.f, s0));
        s1 = fminf(30.f, fmaxf(-30.f, s1));
        float x0 = __expf(s0), x1 = __expf(s1);
        ((float2*)ex_out)[e0] = make_float2(x0, x1);
        atomicAdd(&s_out[d * 2 + 0], x0);
        atomicAdd(&s_out[d * 2 + 1], x1);
    }
    if (v1) {   // edge e1
        int d = col[e1], s = row[e1];
        float s0 = acc10 + sq_dst[d * 2 + 0] + sk_src[s * 2 + 0] + c_s[0];
        float s1 = acc11 + sq_dst[d * 2 + 1] + sk_src[s * 2 + 1] + c_s[1];
        s0 = fminf(30.f, fmaxf(-30.f, s0));
        s1 = fminf(30.f, fmaxf(-30.f, s1));
        float x0 = __expf(s0), x1 = __expf(s1);
        ((float2*)ex_out)[e1] = make_float2(x0, x1);
        atomicAdd(&s_out[d * 2 + 0], x0);
        atomicAdd(&s_out[d * 2 + 1], x1);
    }
}

// ---------------- reciprocal of softmax denominators (in place) ----------------
__global__ __launch_bounds__(256) void recip_kernel(float* __restrict__ s, int n)
{
    int i = blockIdx.x * 256 + threadIdx.x;
    if (i < n) s[i] = __builtin_amdgcn_rcpf(s[i]);
}

// ---------------- edge aggregation: agg[col] += w * (v[row] + rel + eb) ----------------
// wave-per-edge-iteration; e is wave-uniform -> index/attr loads take the
// scalar (SMEM) path; each lane caches its We column in registers.
__global__ __launch_bounds__(256) void edge_agg_kernel(
    const void* __restrict__ ea, const void* __restrict__ We,
    const int* __restrict__ row, const int* __restrict__ col,
    const float* __restrict__ v_src, const void* __restrict__ rel_emb,
    const float* __restrict__ ex_in, const float* __restrict__ inv_s,
    const int* __restrict__ flagp,
    float* __restrict__ agg, int num_e)
{
    const int f32 = *flagp;
    __shared__ float We_s[16 * 64];
    __shared__ float rel_s[64];
    for (int i = threadIdx.x; i < 16 * 64; i += 256) We_s[i] = ldf(We, i, f32);
    if (threadIdx.x < 64) rel_s[threadIdx.x] = ldf(rel_emb, threadIdx.x, f32);
    __syncthreads();

    const int lane   = threadIdx.x & 63;
    const int h      = lane >> 5;
    const int wave   = (blockIdx.x * blockDim.x + threadIdx.x) >> 6;
    const int nwaves = (gridDim.x * blockDim.x) >> 6;

    float Wl[16];
    #pragma unroll
    for (int c = 0; c < 16; ++c) Wl[c] = We_s[c * 64 + lane];
    const float rl = rel_s[lane];

    for (int e = wave; e < num_e; e += nwaves) {
        const int eu = __builtin_amdgcn_readfirstlane(e);
        int r = row[eu];           // scalar loads (uniform index)
        int d = col[eu];
        float ex0 = ex_in[(size_t)eu * 2 + 0];
        float ex1 = ex_in[(size_t)eu * 2 + 1];
        float iv0 = inv_s[d * 2 + 0];
        float iv1 = inv_s[d * 2 + 1];
        float wgt = h ? (ex1 * iv1) : (ex0 * iv0);
        float ebl = 0.f;
        #pragma unroll
        for (int c = 0; c < 16; ++c)
            ebl += ldf(ea, (size_t)eu * 16 + c, f32) * Wl[c];   // uniform -> s_load
        float msg = v_src[(size_t)r * 64 + lane] + rl + ebl;
        atomicAdd(&agg[(size_t)d * 64 + lane], wgt * msg);
    }
}

// ---------------- final: out = agg @ Wo + bo + x @ Wr ----------------
__global__ __launch_bounds__(256) void final_kernel(
    const float* __restrict__ agg, const void* __restrict__ x,
    const void* __restrict__ Wo, const void* __restrict__ bo,
    const void* __restrict__ Wr, const int* __restrict__ flagp,
    void* __restrict__ out, size_t out_elem_off, int n_nodes)
{
    const int f32 = *flagp;
    __shared__ float Wo_s[64 * 32], Wr_s[64 * 32];
    __shared__ float bo_s[32];
    for (int i = threadIdx.x; i < 64 * 32; i += 256) { Wo_s[i] = ldf(Wo, i, f32); Wr_s[i] = ldf(Wr, i, f32); }
    if (threadIdx.x < 32) bo_s[threadIdx.x] = ldf(bo, threadIdx.x, f32);
    __syncthreads();

    const int lane   = threadIdx.x & 63;
    const int j      = lane & 31;
    const int half   = lane >> 5;
    const int wave   = (blockIdx.x * blockDim.x + threadIdx.x) >> 6;
    const int nwaves = (gridDim.x * blockDim.x) >> 6;
    const int pairs  = (n_nodes + 1) >> 1;

    for (int p = wave; p < pairs; p += nwaves) {
        int n = p * 2 + half;
        bool valid = (n < n_nodes);
        int nn = valid ? n : (n_nodes - 1);
        float a0 = agg[(size_t)nn * 64 + j];
        float a1 = agg[(size_t)nn * 64 + 32 + j];
        float x0 = ldf(x, (size_t)nn * 64 + j, f32);
        float x1 = ldf(x, (size_t)nn * 64 + 32 + j, f32);
        float acc = bo_s[j];
        #pragma unroll
        for (int c = 0; c < 32; ++c) {
            float ac0 = __shfl(a0, c, 32);
            float ac1 = __shfl(a1, c, 32);
            float xc0 = __shfl(x0, c, 32);
            float xc1 = __shfl(x1, c, 32);
            acc += ac0 * Wo_s[c * 32 + j] + ac1 * Wo_s[(32 + c) * 32 + j]
                 + xc0 * Wr_s[c * 32 + j] + xc1 * Wr_s[(32 + c) * 32 + j];
        }
        if (valid) stf(out, out_elem_off + (size_t)n * 32 + j, f32, acc);
    }
}

extern "C" void kernel_launch(void* const* d_in, const int* in_sizes, int n_in,
                              void* d_out, int out_size, void* d_ws, size_t ws_size,
                              hipStream_t stream)
{
    const void* x_a   = d_in[0];
    const void* x_b   = d_in[1];
    const void* ea1   = d_in[2];
    const void* ea2   = d_in[3];
    const void* Wq_a  = d_in[4];
    const void* Wk_a  = d_in[5];
    const void* Wv_a  = d_in[6];
    const void* Wq_b  = d_in[7];
    const void* Wk_b  = d_in[8];
    const void* Wv_b  = d_in[9];
    const void* emb_a = d_in[10];
    const void* emb_b = d_in[11];
    const void* rel1  = d_in[12];
    const void* rel2  = d_in[13];
    const void* We    = d_in[14];
    const void* a_at  = d_in[15];
    const void* Wo_a  = d_in[16];
    const void* bo_a  = d_in[17];
    const void* Wo_b  = d_in[18];
    const void* bo_b  = d_in[19];
    const void* Wr_a  = d_in[20];
    const void* Wr_b  = d_in[21];
    const int*  row1  = (const int*)d_in[22];
    const int*  col1  = (const int*)d_in[23];
    const int*  row2  = (const int*)d_in[24];
    const int*  col2  = (const int*)d_in[25];

    const int N = in_sizes[0] / 64;   // nodes per type
    const int E = in_sizes[22];       // edges per relation

    // ---- workspace layout (fp32) ----
    float* ws = (float*)d_ws;
    size_t off = 0;
    int*   flag = (int*)ws; off += 64;             // 256-B header
    float* v_a  = ws + off; off += (size_t)N * 64;
    float* v_b  = ws + off; off += (size_t)N * 64;
    float* sq_a = ws + off; off += (size_t)N * 2;
    float* sk_a = ws + off; off += (size_t)N * 2;
    float* sq_b = ws + off; off += (size_t)N * 2;
    float* sk_b = ws + off; off += (size_t)N * 2;
    float* ex1  = ws + off; off += (size_t)E * 2;
    float* ex2  = ws + off; off += (size_t)E * 2;
    float* cvals = ws + off; off += 4;
    // zero-initialized region (contiguous, single memset)
    float* zero_base = ws + off;
    float* s1    = ws + off; off += (size_t)N * 2;
    float* s2    = ws + off; off += (size_t)N * 2;
    float* agg_a = ws + off; off += (size_t)N * 64;
    float* agg_b = ws + off; off += (size_t)N * 64;
    size_t zero_bytes = (size_t)(N * 2 * 2 + N * 64 * 2) * sizeof(float);

    const int node_blocks  = (N * 64 + 255) / 256;                 // wave-per-node
    const int score_blocks = (E + 511) / 512;                      // thread per 2 edges
    const int agg_blocks   = 4096;                                 // grid-stride waves
    const int fin_blocks   = ((((N + 1) / 2) * 64) + 255) / 256;   // wave-per-2-nodes

    detect_kernel<<<1, 128, 0, stream>>>((const unsigned short*)a_at, flag);
    hipMemsetAsync(zero_base, 0, zero_bytes, stream);

    node_prep_kernel<<<node_blocks, 256, 0, stream>>>(x_a, Wq_a, Wk_a, Wv_a, emb_a, a_at, flag, v_a, sq_a, sk_a, N);
    node_prep_kernel<<<node_blocks, 256, 0, stream>>>(x_b, Wq_b, Wk_b, Wv_b, emb_b, a_at, flag, v_b, sq_b, sk_b, N);
    rel_const_kernel<<<1, 128, 0, stream>>>(rel1, rel2, a_at, flag, cvals);

    // relation 1: a -> b ; relation 2: b -> a
    edge_score_kernel<<<score_blocks, 256, 0, stream>>>(ea1, We, row1, col1, sq_b, sk_a, cvals + 0, a_at, flag, ex1, s1, E);
    edge_score_kernel<<<score_blocks, 256, 0, stream>>>(ea2, We, row2, col2, sq_a, sk_b, cvals + 2, a_at, flag, ex2, s2, E);

    recip_kernel<<<(N * 4 + 255) / 256, 256, 0, stream>>>(s1, N * 4);   // s1 & s2 contiguous

    edge_agg_kernel<<<agg_blocks, 256, 0, stream>>>(ea1, We, row1, col1, v_a, rel1, ex1, s1, flag, agg_b, E);
    edge_agg_kernel<<<agg_blocks, 256, 0, stream>>>(ea2, We, row2, col2, v_b, rel2, ex2, s2, flag, agg_a, E);

    final_kernel<<<fin_blocks, 256, 0, stream>>>(agg_a, x_a, Wo_a, bo_a, Wr_a, flag, d_out, 0, N);
    final_kernel<<<fin_blocks, 256, 0, stream>>>(agg_b, x_b, Wo_b, bo_b, Wr_b, flag, d_out, (size_t)N * 32, N);
}

// Round 4
// 1193.498 us; speedup vs baseline: 2.3858x; 2.2309x over previous
//
#include <hip/hip_runtime.h>
#include <hip/hip_bf16.h>

typedef __hip_bfloat16 bf16;

static __device__ __forceinline__ float b2f(bf16 x) { return __bfloat162float(x); }

// dtype-dispatched load/store: f32=1 -> buffer is float32, f32=0 -> bfloat16.
static __device__ __forceinline__ float ldf(const void* p, size_t i, int f32) {
    return f32 ? ((const float*)p)[i] : b2f(((const bf16*)p)[i]);
}
static __device__ __forceinline__ void stf(void* p, size_t i, int f32, float v) {
    if (f32) ((float*)p)[i] = v;
    else     ((bf16*)p)[i] = __float2bfloat16(v);
}

// fast tanh: 1 - 2/(e^2x + 1)
static __device__ __forceinline__ float fast_tanh(float x) {
    float t = __expf(2.f * x);
    return 1.f - 2.f * __builtin_amdgcn_rcpf(t + 1.f);
}

// load 16 edge-attr channels of edge e into registers (either dtype)
static __device__ __forceinline__ void load_ea16(const void* ea, size_t e, int f32, float* er) {
    if (f32) {
        const float4* p = (const float4*)((const float*)ea + e * 16);
        #pragma unroll
        for (int q = 0; q < 4; ++q) {
            float4 v = p[q];
            er[4*q] = v.x; er[4*q+1] = v.y; er[4*q+2] = v.z; er[4*q+3] = v.w;
        }
    } else {
        const uint4* p = (const uint4*)((const bf16*)ea + e * 16);
        #pragma unroll
        for (int q = 0; q < 2; ++q) {
            uint4 u = p[q];
            er[8*q+0] = __uint_as_float(u.x << 16);
            er[8*q+1] = __uint_as_float(u.x & 0xffff0000u);
            er[8*q+2] = __uint_as_float(u.y << 16);
            er[8*q+3] = __uint_as_float(u.y & 0xffff0000u);
            er[8*q+4] = __uint_as_float(u.z << 16);
            er[8*q+5] = __uint_as_float(u.z & 0xffff0000u);
            er[8*q+6] = __uint_as_float(u.w << 16);
            er[8*q+7] = __uint_as_float(u.w & 0xffff0000u);
        }
    }
}

// ---------------- dtype detector ----------------
__global__ void detect_kernel(const unsigned short* __restrict__ a, int* __restrict__ flag)
{
    __shared__ int cnt;
    if (threadIdx.x == 0) cnt = 0;
    __syncthreads();
    unsigned e = (a[threadIdx.x] >> 7) & 0xFF;
    if (e < 100 || e > 133) atomicAdd(&cnt, 1);
    __syncthreads();
    if (threadIdx.x == 0) *flag = (cnt >= 16) ? 1 : 0;   // 1 => float32 tensors
}

// ---------------- node prep: v projection + per-node score scalars ----------------
__global__ __launch_bounds__(256) void node_prep_kernel(
    const void* __restrict__ x, const void* __restrict__ Wq,
    const void* __restrict__ Wk, const void* __restrict__ Wv,
    const void* __restrict__ emb, const void* __restrict__ a_attn,
    const int* __restrict__ flagp,
    float* __restrict__ v_out, float* __restrict__ sq_out, float* __restrict__ sk_out,
    int n_nodes)
{
    const int f32 = *flagp;
    __shared__ float Wq_s[64 * 64], Wk_s[64 * 64], Wv_s[64 * 64];
    __shared__ float emb_s[64], a_s[64];
    for (int i = threadIdx.x; i < 64 * 64; i += 256) {
        Wq_s[i] = ldf(Wq, i, f32); Wk_s[i] = ldf(Wk, i, f32); Wv_s[i] = ldf(Wv, i, f32);
    }
    if (threadIdx.x < 64) {
        emb_s[threadIdx.x] = ldf(emb, threadIdx.x, f32);
        a_s[threadIdx.x]   = ldf(a_attn, threadIdx.x, f32);
    }
    __syncthreads();

    const int lane   = threadIdx.x & 63;
    const int wave   = (blockIdx.x * blockDim.x + threadIdx.x) >> 6;
    const int nwaves = (gridDim.x * blockDim.x) >> 6;

    for (int n = wave; n < n_nodes; n += nwaves) {
        float xv = ldf(x, (size_t)n * 64 + lane, f32);
        float q = 0.f, k = 0.f, v = 0.f;
        #pragma unroll
        for (int c = 0; c < 64; ++c) {
            float xc = __shfl(xv, c, 64);
            q += xc * Wq_s[c * 64 + lane];
            k += xc * Wk_s[c * 64 + lane];
            v += xc * Wv_s[c * 64 + lane];
        }
        v_out[(size_t)n * 64 + lane] = v;
        float tq = fast_tanh(q + emb_s[lane]) * a_s[lane & 31];
        float tk = fast_tanh(k + emb_s[lane]) * a_s[32 + (lane & 31)];
        #pragma unroll
        for (int off = 16; off; off >>= 1) {
            tq += __shfl_xor(tq, off, 32);
            tk += __shfl_xor(tk, off, 32);
        }
        if ((lane & 31) == 0) {
            int h = lane >> 5;
            sq_out[n * 2 + h] = tq;
            sk_out[n * 2 + h] = tk;
        }
    }
}

// ---------------- relation constants: c[h] = sum_j tanh(rel[h,j]) * a[64+j'] ----------------
__global__ void rel_const_kernel(const void* __restrict__ rel1, const void* __restrict__ rel2,
                                 const void* __restrict__ a_attn, const int* __restrict__ flagp,
                                 float* __restrict__ cvals)
{
    const int f32 = *flagp;
    int t = threadIdx.x;             // 128 threads: wave0 -> rel1, wave1 -> rel2
    const void* r = (t < 64) ? rel1 : rel2;
    int l = t & 63;
    float v = tanhf(ldf(r, l, f32)) * ldf(a_attn, 64 + (l & 31), f32);
    #pragma unroll
    for (int off = 16; off; off >>= 1) v += __shfl_xor(v, off, 32);
    if ((l & 31) == 0) cvals[(t >> 6) * 2 + (l >> 5)] = v;
}

// ---------------- precompute: M = blockdiag(We@Wo) [32x32], c32 = rel@Wo [32] ----------------
__global__ void precompute_kernel(const void* __restrict__ We, const void* __restrict__ Wo,
                                  const void* __restrict__ rel, const int* __restrict__ flagp,
                                  float* __restrict__ M, float* __restrict__ c32)
{
    const int f32 = *flagp;
    int t = threadIdx.x;            // 1024 threads
    int m = t >> 5, j = t & 31;
    int h = m >> 4, c = m & 15;
    float s = 0.f;
    for (int jj = 0; jj < 32; ++jj)
        s += ldf(We, c * 64 + h * 32 + jj, f32) * ldf(Wo, (size_t)(h * 32 + jj) * 32 + j, f32);
    M[m * 32 + j] = s;
    if (t < 32) {
        float s2 = 0.f;
        for (int ch = 0; ch < 64; ++ch)
            s2 += ldf(rel, ch, f32) * ldf(Wo, (size_t)ch * 32 + t, f32);
        c32[t] = s2;
    }
}

// ---------------- edge scores: thread per 2 edges, rolled jb loop (no spills) ----------------
__global__ __launch_bounds__(256) void edge_score_kernel(
    const void* __restrict__ ea, const void* __restrict__ We,
    const int* __restrict__ row, const int* __restrict__ col,
    const float* __restrict__ sq_dst, const float* __restrict__ sk_src,
    const float* __restrict__ cvals, const void* __restrict__ a_attn,
    const int* __restrict__ flagp,
    float* __restrict__ ex_out, int num_e)
{
    const int f32 = *flagp;
    __shared__ float We_s[16 * 64];
    __shared__ float a3_s[32];
    __shared__ float c_s[2];
    for (int i = threadIdx.x; i < 16 * 64; i += 256) We_s[i] = ldf(We, i, f32);
    if (threadIdx.x < 32) a3_s[threadIdx.x] = ldf(a_attn, 96 + threadIdx.x, f32);
    if (threadIdx.x < 2)  c_s[threadIdx.x]  = cvals[threadIdx.x];
    __syncthreads();

    const int e0 = blockIdx.x * 512 + threadIdx.x;
    const int e1 = e0 + 256;
    const bool v1 = (e1 < num_e);
    if (e0 >= num_e) return;

    float er0[16], er1[16];
    load_ea16(ea, (size_t)e0, f32, er0);
    if (v1) load_ea16(ea, (size_t)e1, f32, er1);
    else {
        #pragma unroll
        for (int c = 0; c < 16; ++c) er1[c] = 0.f;
    }

    float acc00 = 0.f, acc01 = 0.f, acc10 = 0.f, acc11 = 0.f;
    #pragma unroll 1                       // keep rolled: avoids VGPR blowup/spills
    for (int jb = 0; jb < 64; jb += 16) {
        float t0[16], t1[16];
        #pragma unroll
        for (int jj = 0; jj < 16; ++jj) { t0[jj] = 0.f; t1[jj] = 0.f; }
        #pragma unroll
        for (int c = 0; c < 16; ++c) {
            #pragma unroll
            for (int jj = 0; jj < 16; ++jj) {
                float w = We_s[c * 64 + jb + jj];   // uniform broadcast, b128-merged
                t0[jj] += er0[c] * w;
                t1[jj] += er1[c] * w;
            }
        }
        float p0 = 0.f, p1 = 0.f;
        #pragma unroll
        for (int jj = 0; jj < 16; ++jj) {
            float a = a3_s[(jb + jj) & 31];
            p0 += fast_tanh(t0[jj]) * a;
            p1 += fast_tanh(t1[jj]) * a;
        }
        if (jb & 32) { acc01 += p0; acc11 += p1; }
        else         { acc00 += p0; acc10 += p1; }
    }

    {
        int d = col[e0], s = row[e0];
        float2 sqd = ((const float2*)sq_dst)[d];
        float2 sks = ((const float2*)sk_src)[s];
        float s0 = fminf(30.f, fmaxf(-30.f, acc00 + sqd.x + sks.x + c_s[0]));
        float s1 = fminf(30.f, fmaxf(-30.f, acc01 + sqd.y + sks.y + c_s[1]));
        ((float2*)ex_out)[e0] = make_float2(__expf(s0), __expf(s1));
    }
    if (v1) {
        int d = col[e1], s = row[e1];
        float2 sqd = ((const float2*)sq_dst)[d];
        float2 sks = ((const float2*)sk_src)[s];
        float s0 = fminf(30.f, fmaxf(-30.f, acc10 + sqd.x + sks.x + c_s[0]));
        float s1 = fminf(30.f, fmaxf(-30.f, acc11 + sqd.y + sks.y + c_s[1]));
        ((float2*)ex_out)[e1] = make_float2(__expf(s0), __expf(s1));
    }
}

// ---------------- CSR build ----------------
__global__ __launch_bounds__(256) void hist_kernel(const int* __restrict__ col,
                                                   int* __restrict__ cnt, int rb, int num_e)
{
    int e = blockIdx.x * 256 + threadIdx.x;
    if (e < num_e) atomicAdd(&cnt[rb + col[e]], 1);
}

__global__ __launch_bounds__(256) void scan1_kernel(const int* __restrict__ cnt,
                                                    int* __restrict__ partial, int n)
{
    __shared__ int wsum[4];
    int t = threadIdx.x;
    int i0 = blockIdx.x * 512 + 2 * t;
    int s = ((i0 < n) ? cnt[i0] : 0) + ((i0 + 1 < n) ? cnt[i0 + 1] : 0);
    #pragma unroll
    for (int o = 32; o; o >>= 1) s += __shfl_xor(s, o, 64);
    if ((t & 63) == 0) wsum[t >> 6] = s;
    __syncthreads();
    if (t == 0) partial[blockIdx.x] = wsum[0] + wsum[1] + wsum[2] + wsum[3];
}

__global__ void scan2_kernel(const int* __restrict__ partial, int* __restrict__ pp,
                             int* __restrict__ off, int nch, int noff)
{
    int lane = threadIdx.x;   // 64 threads
    int running = 0;
    for (int base = 0; base < nch; base += 64) {
        int i = base + lane;
        int o = (i < nch) ? partial[i] : 0;
        int v = o;
        #pragma unroll
        for (int d = 1; d < 64; d <<= 1) {
            int u = __shfl_up(v, d, 64);
            if (lane >= d) v += u;
        }
        if (i < nch) pp[i] = running + v - o;
        running += __shfl(v, 63, 64);
    }
    if (lane == 0) off[noff] = running;
}

__global__ __launch_bounds__(256) void scan3_kernel(const int* __restrict__ cnt,
                                                    const int* __restrict__ pp,
                                                    int* __restrict__ off,
                                                    int* __restrict__ cursor, int n)
{
    __shared__ int tmp[256];
    int t = threadIdx.x;
    int i0 = blockIdx.x * 512 + 2 * t;
    int v0 = (i0 < n) ? cnt[i0] : 0;
    int v1 = (i0 + 1 < n) ? cnt[i0 + 1] : 0;
    int pair = v0 + v1;
    tmp[t] = pair;
    __syncthreads();
    for (int d = 1; d < 256; d <<= 1) {
        int x = (t >= d) ? tmp[t - d] : 0;
        __syncthreads();
        tmp[t] += x;
        __syncthreads();
    }
    int excl = tmp[t] - pair + pp[blockIdx.x];
    if (i0 < n)     { off[i0] = excl;          cursor[i0] = excl; }
    if (i0 + 1 < n) { off[i0 + 1] = excl + v0; cursor[i0 + 1] = excl + v0; }
}

__global__ __launch_bounds__(256) void scatter_kernel(
    const int* __restrict__ row, const int* __restrict__ col,
    const float2* __restrict__ ex, int* __restrict__ cursor,
    uint4* __restrict__ payload, int rb, int num_e)
{
    int e = blockIdx.x * 256 + threadIdx.x;
    if (e >= num_e) return;
    int pos = atomicAdd(&cursor[rb + col[e]], 1);
    float2 x2 = ex[e];
    payload[pos] = make_uint4((unsigned)row[e], __float_as_uint(x2.x),
                              __float_as_uint(x2.y), (unsigned)e);
}

// ---------------- fused aggregation + output projection (CSR, no atomics) ----------------
// wave per dst (grid-stride). agg = y + rel + u@We with y = sum w*v[row],
// u = sum w*ea. out = agg@Wo + bo + x@Wr = y@Wo + u@M + deg?c32 + bo + x@Wr.
__global__ __launch_bounds__(256) void agg_final_kernel(
    const uint4* __restrict__ payload, const int* __restrict__ off,
    const float* __restrict__ v_src, const void* __restrict__ x,
    const void* __restrict__ ea, const void* __restrict__ Wo,
    const void* __restrict__ bo, const void* __restrict__ Wr,
    const float* __restrict__ M, const float* __restrict__ c32,
    const int* __restrict__ flagp, void* __restrict__ out,
    size_t out_elem_off, int relbase, int n_nodes)
{
    const int f32  = *flagp;
    const int lane = threadIdx.x & 63;
    const int wv   = threadIdx.x >> 6;
    const int j    = lane & 31;
    const int half = lane >> 5;

    __shared__ float stage[4][160];   // per-wave: y[64] | x[64] | u[32]

    // per-lane weight columns (half-split over c): 80 VGPRs, loaded once
    float WoR[32], WrR[32], MR[16];
    const int cb = half * 32;
    #pragma unroll
    for (int cc = 0; cc < 32; ++cc) {
        WoR[cc] = ldf(Wo, (size_t)(cb + cc) * 32 + j, f32);
        WrR[cc] = ldf(Wr, (size_t)(cb + cc) * 32 + j, f32);
    }
    const int ub = half * 16;
    #pragma unroll
    for (int cc = 0; cc < 16; ++cc) MR[cc] = M[(ub + cc) * 32 + j];
    const float boR  = ldf(bo, j, f32);
    const float c32R = c32[j];

    const int stride = gridDim.x * 4;
    const int iters  = (n_nodes + stride - 1) / stride;
    int d = blockIdx.x * 4 + wv;

    for (int it = 0; it < iters; ++it, d += stride) {
        const bool valid = (d < n_nodes);
        const int dd  = valid ? d : (n_nodes - 1);
        const int idx = relbase + dd;
        const int b   = __builtin_amdgcn_readfirstlane(off[idx]);
        const int en  = __builtin_amdgcn_readfirstlane(off[idx + 1]);
        const int deg = en - b;

        // pass 1: softmax denominators (uniform scalar loads)
        float den0 = 0.f, den1 = 0.f;
        #pragma unroll 4
        for (int k = b; k < en; ++k) {
            uint4 p = payload[k];
            den0 += __uint_as_float(p.y);
            den1 += __uint_as_float(p.z);
        }
        float inv0 = (deg > 0) ? __builtin_amdgcn_rcpf(den0) : 0.f;
        float inv1 = (deg > 0) ? __builtin_amdgcn_rcpf(den1) : 0.f;
        const float invh = (lane < 32) ? inv0 : inv1;

        // pass 2: y, u accumulation
        float y = 0.f, uacc = 0.f;
        const int c16 = lane & 15;
        #pragma unroll 2
        for (int k = b; k < en; ++k) {
            uint4 p = payload[k];
            float exh = (lane < 32) ? __uint_as_float(p.y) : __uint_as_float(p.z);
            float w = exh * invh;
            float vv = v_src[(size_t)p.x * 64 + lane];
            y = fmaf(w, vv, y);
            float eav = ldf(ea, (size_t)p.w * 16 + c16, f32);
            uacc = fmaf(w, eav, uacc);
        }

        float xv = ldf(x, (size_t)dd * 64 + lane, f32);

        // stage through LDS for lane->channel transpose
        float* st = stage[wv];
        st[lane] = y;
        st[64 + lane] = xv;
        if ((lane & 31) < 16) st[128 + half * 16 + c16] = uacc;
        __syncthreads();

        float acc = 0.f;
        #pragma unroll
        for (int cc = 0; cc < 32; ++cc) {
            acc = fmaf(st[cb + cc], WoR[cc], acc);
            acc = fmaf(st[64 + cb + cc], WrR[cc], acc);
        }
        #pragma unroll
        for (int cc = 0; cc < 16; ++cc)
            acc = fmaf(st[128 + ub + cc], MR[cc], acc);

        float other = __shfl(acc, lane ^ 32, 64);
        if (valid && lane < 32) {
            float o = acc + other + boR + ((deg > 0) ? c32R : 0.f);
            stf(out, out_elem_off + (size_t)dd * 32 + j, f32, o);
        }
        __syncthreads();
    }
}

extern "C" void kernel_launch(void* const* d_in, const int* in_sizes, int n_in,
                              void* d_out, int out_size, void* d_ws, size_t ws_size,
                              hipStream_t stream)
{
    const void* x_a   = d_in[0];
    const void* x_b   = d_in[1];
    const void* ea1   = d_in[2];
    const void* ea2   = d_in[3];
    const void* Wq_a  = d_in[4];
    const void* Wk_a  = d_in[5];
    const void* Wv_a  = d_in[6];
    const void* Wq_b  = d_in[7];
    const void* Wk_b  = d_in[8];
    const void* Wv_b  = d_in[9];
    const void* emb_a = d_in[10];
    const void* emb_b = d_in[11];
    const void* rel1  = d_in[12];
    const void* rel2  = d_in[13];
    const void* We    = d_in[14];
    const void* a_at  = d_in[15];
    const void* Wo_a  = d_in[16];
    const void* bo_a  = d_in[17];
    const void* Wo_b  = d_in[18];
    const void* bo_b  = d_in[19];
    const void* Wr_a  = d_in[20];
    const void* Wr_b  = d_in[21];
    const int*  row1  = (const int*)d_in[22];
    const int*  col1  = (const int*)d_in[23];
    const int*  row2  = (const int*)d_in[24];
    const int*  col2  = (const int*)d_in[25];

    const int N = in_sizes[0] / 64;   // nodes per type
    const int E = in_sizes[22];       // edges per relation

    // ---- workspace layout ----
    float* ws = (float*)d_ws;
    size_t off = 0;
    int*   flag = (int*)ws;        off += 64;
    float* v_a  = ws + off;        off += (size_t)N * 64;
    float* v_b  = ws + off;        off += (size_t)N * 64;
    float* sq_a = ws + off;        off += (size_t)N * 2;
    float* sk_a = ws + off;        off += (size_t)N * 2;
    float* sq_b = ws + off;        off += (size_t)N * 2;
    float* sk_b = ws + off;        off += (size_t)N * 2;
    float* cvals = ws + off;       off += 4;
    float* ex1  = ws + off;        off += (size_t)E * 2;
    float* ex2  = ws + off;        off += (size_t)E * 2;
    float* M1   = ws + off;        off += 1024;
    float* c321 = ws + off;        off += 32;
    float* M2   = ws + off;        off += 1024;
    float* c322 = ws + off;        off += 32;
    int*   cnt    = (int*)(ws + off);  off += (size_t)2 * N;
    int*   offs   = (int*)(ws + off);  off += (size_t)2 * N + 2;
    int*   cursor = (int*)(ws + off);  off += (size_t)2 * N;
    int*   partial = (int*)(ws + off); off += 512;
    int*   pp      = (int*)(ws + off); off += 512;
    off = (off + 3) & ~(size_t)3;     // 16B align for uint4
    uint4* payload = (uint4*)(ws + off); off += (size_t)2 * E * 4;

    const int node_blocks  = (N * 64 + 255) / 256;
    const int score_blocks = (E + 511) / 512;
    const int eb_blocks    = (E + 255) / 256;
    const int nch          = (2 * N + 511) / 512;
    const int agg_blocks   = 2048;

    detect_kernel<<<1, 128, 0, stream>>>((const unsigned short*)a_at, flag);
    hipMemsetAsync(cnt, 0, (size_t)2 * N * sizeof(int), stream);

    node_prep_kernel<<<node_blocks, 256, 0, stream>>>(x_a, Wq_a, Wk_a, Wv_a, emb_a, a_at, flag, v_a, sq_a, sk_a, N);
    node_prep_kernel<<<node_blocks, 256, 0, stream>>>(x_b, Wq_b, Wk_b, Wv_b, emb_b, a_at, flag, v_b, sq_b, sk_b, N);
    rel_const_kernel<<<1, 128, 0, stream>>>(rel1, rel2, a_at, flag, cvals);
    precompute_kernel<<<1, 1024, 0, stream>>>(We, Wo_b, rel1, flag, M1, c321);  // rel1 -> out_b
    precompute_kernel<<<1, 1024, 0, stream>>>(We, Wo_a, rel2, flag, M2, c322);  // rel2 -> out_a

    hist_kernel<<<eb_blocks, 256, 0, stream>>>(col1, cnt, 0, E);
    hist_kernel<<<eb_blocks, 256, 0, stream>>>(col2, cnt, N, E);
    scan1_kernel<<<nch, 256, 0, stream>>>(cnt, partial, 2 * N);
    scan2_kernel<<<1, 64, 0, stream>>>(partial, pp, offs, nch, 2 * N);
    scan3_kernel<<<nch, 256, 0, stream>>>(cnt, pp, offs, cursor, 2 * N);

    edge_score_kernel<<<score_blocks, 256, 0, stream>>>(ea1, We, row1, col1, sq_b, sk_a, cvals + 0, a_at, flag, ex1, E);
    edge_score_kernel<<<score_blocks, 256, 0, stream>>>(ea2, We, row2, col2, sq_a, sk_b, cvals + 2, a_at, flag, ex2, E);

    scatter_kernel<<<eb_blocks, 256, 0, stream>>>(row1, col1, (const float2*)ex1, cursor, payload, 0, E);
    scatter_kernel<<<eb_blocks, 256, 0, stream>>>(row2, col2, (const float2*)ex2, cursor, payload, N, E);

    // rel1: src a -> dst b (out_b at element offset N*32); rel2: src b -> dst a
    agg_final_kernel<<<agg_blocks, 256, 0, stream>>>(payload, offs, v_a, x_b, ea1, Wo_b, bo_b, Wr_b,
                                                     M1, c321, flag, d_out, (size_t)N * 32, 0, N);
    agg_final_kernel<<<agg_blocks, 256, 0, stream>>>(payload, offs, v_b, x_a, ea2, Wo_a, bo_a, Wr_a,
                                                     M2, c322, flag, d_out, 0, N, N);
}

// Round 5
// 954.970 us; speedup vs baseline: 2.9817x; 1.2498x over previous
//
#include <hip/hip_runtime.h>
#include <hip/hip_bf16.h>

typedef __hip_bfloat16 bf16;
typedef __attribute__((ext_vector_type(8))) short short8;
typedef __attribute__((ext_vector_type(4))) float float4v;

static __device__ __forceinline__ float b2f(bf16 x) { return __bfloat162float(x); }

// dtype-dispatched load/store: f32=1 -> buffer is float32, f32=0 -> bfloat16.
static __device__ __forceinline__ float ldf(const void* p, size_t i, int f32) {
    return f32 ? ((const float*)p)[i] : b2f(((const bf16*)p)[i]);
}
static __device__ __forceinline__ void stf(void* p, size_t i, int f32, float v) {
    if (f32) ((float*)p)[i] = v;
    else     ((bf16*)p)[i] = __float2bfloat16(v);
}

// fast tanh: 1 - 2/(e^2x + 1)
static __device__ __forceinline__ float fast_tanh(float x) {
    float t = __expf(2.f * x);
    return 1.f - 2.f * __builtin_amdgcn_rcpf(t + 1.f);
}

// load 16 edge-attr channels of edge e into registers (either dtype)
static __device__ __forceinline__ void load_ea16(const void* ea, size_t e, int f32, float* er) {
    if (f32) {
        const float4* p = (const float4*)((const float*)ea + e * 16);
        #pragma unroll
        for (int q = 0; q < 4; ++q) {
            float4 v = p[q];
            er[4*q] = v.x; er[4*q+1] = v.y; er[4*q+2] = v.z; er[4*q+3] = v.w;
        }
    } else {
        const uint4* p = (const uint4*)((const bf16*)ea + e * 16);
        #pragma unroll
        for (int q = 0; q < 2; ++q) {
            uint4 u = p[q];
            er[8*q+0] = __uint_as_float(u.x << 16);
            er[8*q+1] = __uint_as_float(u.x & 0xffff0000u);
            er[8*q+2] = __uint_as_float(u.y << 16);
            er[8*q+3] = __uint_as_float(u.y & 0xffff0000u);
            er[8*q+4] = __uint_as_float(u.z << 16);
            er[8*q+5] = __uint_as_float(u.z & 0xffff0000u);
            er[8*q+6] = __uint_as_float(u.w << 16);
            er[8*q+7] = __uint_as_float(u.w & 0xffff0000u);
        }
    }
}

// ---------------- dtype detector ----------------
__global__ void detect_kernel(const unsigned short* __restrict__ a, int* __restrict__ flag)
{
    __shared__ int cnt;
    if (threadIdx.x == 0) cnt = 0;
    __syncthreads();
    unsigned e = (a[threadIdx.x] >> 7) & 0xFF;
    if (e < 100 || e > 133) atomicAdd(&cnt, 1);
    __syncthreads();
    if (threadIdx.x == 0) *flag = (cnt >= 16) ? 1 : 0;   // 1 => float32 tensors
}

// ---------------- node prep: v projection + per-node score scalars ----------------
// bf16 path: MFMA 16x16x32; wave per 16-node tile, W fragments resident in VGPRs.
// f32 path (fallback): original LDS/shuffle version.
__global__ __launch_bounds__(256) void node_prep_kernel(
    const void* __restrict__ x, const void* __restrict__ Wq,
    const void* __restrict__ Wk, const void* __restrict__ Wv,
    const void* __restrict__ emb, const void* __restrict__ a_attn,
    const int* __restrict__ flagp,
    float* __restrict__ v_out, float* __restrict__ sq_out, float* __restrict__ sk_out,
    int n_nodes)
{
    const int f32 = *flagp;
    __shared__ float Wq_s[64 * 64], Wk_s[64 * 64], Wv_s[64 * 64];
    __shared__ float emb_s[64], a_s[64];

    if (f32) {
        // ---------- fallback path (fp32 tensors) ----------
        for (int i = threadIdx.x; i < 64 * 64; i += 256) {
            Wq_s[i] = ldf(Wq, i, 1); Wk_s[i] = ldf(Wk, i, 1); Wv_s[i] = ldf(Wv, i, 1);
        }
        if (threadIdx.x < 64) {
            emb_s[threadIdx.x] = ldf(emb, threadIdx.x, 1);
            a_s[threadIdx.x]   = ldf(a_attn, threadIdx.x, 1);
        }
        __syncthreads();

        const int lane   = threadIdx.x & 63;
        const int wave   = (blockIdx.x * blockDim.x + threadIdx.x) >> 6;
        const int nwaves = (gridDim.x * blockDim.x) >> 6;

        for (int n = wave; n < n_nodes; n += nwaves) {
            float xv = ldf(x, (size_t)n * 64 + lane, 1);
            float q = 0.f, k = 0.f, v = 0.f;
            #pragma unroll
            for (int c = 0; c < 64; ++c) {
                float xc = __shfl(xv, c, 64);
                q += xc * Wq_s[c * 64 + lane];
                k += xc * Wk_s[c * 64 + lane];
                v += xc * Wv_s[c * 64 + lane];
            }
            v_out[(size_t)n * 64 + lane] = v;
            float tq = fast_tanh(q + emb_s[lane]) * a_s[lane & 31];
            float tk = fast_tanh(k + emb_s[lane]) * a_s[32 + (lane & 31)];
            #pragma unroll
            for (int off = 16; off; off >>= 1) {
                tq += __shfl_xor(tq, off, 32);
                tk += __shfl_xor(tk, off, 32);
            }
            if ((lane & 31) == 0) {
                int h = lane >> 5;
                sq_out[n * 2 + h] = tq;
                sk_out[n * 2 + h] = tk;
            }
        }
        return;
    }

    // ---------- bf16 MFMA path ----------
    const int lane = threadIdx.x & 63;
    const int ml   = lane & 15;        // col-within-tile (D) / node row (A)
    const int g    = lane >> 4;        // quad
    const int g8   = g * 8;

    // per-lane epilogue constants
    float embc[4], acq[4], ack[4];
    #pragma unroll
    for (int t = 0; t < 4; ++t) {
        int colt = t * 16 + ml;
        embc[t] = b2f(((const bf16*)emb)[colt]);
        acq[t]  = b2f(((const bf16*)a_attn)[colt & 31]);
        ack[t]  = b2f(((const bf16*)a_attn)[32 + (colt & 31)]);
    }

    // B fragments: B[k][n], lane holds k = g*8+j (+32 per k-half), n = ml.
    short8 Bq[4][2], Bk[4][2], Bv[4][2];
    const unsigned short* wq = (const unsigned short*)Wq;
    const unsigned short* wk = (const unsigned short*)Wk;
    const unsigned short* wv = (const unsigned short*)Wv;
    #pragma unroll
    for (int t = 0; t < 4; ++t) {
        #pragma unroll
        for (int kh = 0; kh < 2; ++kh) {
            short8 bq, bk, bv;
            #pragma unroll
            for (int j = 0; j < 8; ++j) {
                int idx = (kh * 32 + g8 + j) * 64 + t * 16 + ml;
                bq[j] = (short)wq[idx];
                bk[j] = (short)wk[idx];
                bv[j] = (short)wv[idx];
            }
            Bq[t][kh] = bq; Bk[t][kh] = bk; Bv[t][kh] = bv;
        }
    }

    const int ntiles  = (n_nodes + 15) >> 4;
    const int gw      = (blockIdx.x * blockDim.x + threadIdx.x) >> 6;
    const int gstride = (gridDim.x * blockDim.x) >> 6;
    const unsigned short* xp = (const unsigned short*)x;

    for (int tile = gw; tile < ntiles; tile += gstride) {
        const int n0 = tile << 4;
        int nr = n0 + ml; if (nr > n_nodes - 1) nr = n_nodes - 1;
        const uint4* xr = (const uint4*)(xp + (size_t)nr * 64);
        uint4 ua0 = xr[g];        // k = 0..31 slice (this lane's 8 elems)
        uint4 ua1 = xr[4 + g];    // k = 32..63
        short8 A0 = __builtin_bit_cast(short8, ua0);
        short8 A1 = __builtin_bit_cast(short8, ua1);

        float4v accq[4], acck[4], accv[4];
        #pragma unroll
        for (int t = 0; t < 4; ++t) {
            float4v z = {0.f, 0.f, 0.f, 0.f};
            accq[t] = z; acck[t] = z; accv[t] = z;
        }
        #pragma unroll
        for (int t = 0; t < 4; ++t) {
            accq[t] = __builtin_amdgcn_mfma_f32_16x16x32_bf16(A0, Bq[t][0], accq[t], 0, 0, 0);
            accq[t] = __builtin_amdgcn_mfma_f32_16x16x32_bf16(A1, Bq[t][1], accq[t], 0, 0, 0);
            acck[t] = __builtin_amdgcn_mfma_f32_16x16x32_bf16(A0, Bk[t][0], acck[t], 0, 0, 0);
            acck[t] = __builtin_amdgcn_mfma_f32_16x16x32_bf16(A1, Bk[t][1], acck[t], 0, 0, 0);
            accv[t] = __builtin_amdgcn_mfma_f32_16x16x32_bf16(A0, Bv[t][0], accv[t], 0, 0, 0);
            accv[t] = __builtin_amdgcn_mfma_f32_16x16x32_bf16(A1, Bv[t][1], accv[t], 0, 0, 0);
        }

        // v store: D col = ml, row(node) = g*4 + r
        #pragma unroll
        for (int t = 0; t < 4; ++t) {
            #pragma unroll
            for (int r = 0; r < 4; ++r) {
                int node = n0 + g * 4 + r;
                if (node < n_nodes) v_out[(size_t)node * 64 + t * 16 + ml] = accv[t][r];
            }
        }

        // score scalars: tq[node] = sum_col tanh(q+emb)*a, head-split (t<2 vs t>=2)
        #pragma unroll
        for (int r = 0; r < 4; ++r) {
            float q0 = fast_tanh(accq[0][r] + embc[0]) * acq[0]
                     + fast_tanh(accq[1][r] + embc[1]) * acq[1];
            float q1 = fast_tanh(accq[2][r] + embc[2]) * acq[2]
                     + fast_tanh(accq[3][r] + embc[3]) * acq[3];
            float k0 = fast_tanh(acck[0][r] + embc[0]) * ack[0]
                     + fast_tanh(acck[1][r] + embc[1]) * ack[1];
            float k1 = fast_tanh(acck[2][r] + embc[2]) * ack[2]
                     + fast_tanh(acck[3][r] + embc[3]) * ack[3];
            #pragma unroll
            for (int o = 1; o < 16; o <<= 1) {
                q0 += __shfl_xor(q0, o, 64); q1 += __shfl_xor(q1, o, 64);
                k0 += __shfl_xor(k0, o, 64); k1 += __shfl_xor(k1, o, 64);
            }
            int node = n0 + g * 4 + r;
            if (ml == 0 && node < n_nodes) {
                ((float2*)sq_out)[node] = make_float2(q0, q1);
                ((float2*)sk_out)[node] = make_float2(k0, k1);
            }
        }
    }
}

// ---------------- relation constants: c[h] = sum_j tanh(rel[h,j]) * a[64+j'] ----------------
__global__ void rel_const_kernel(const void* __restrict__ rel1, const void* __restrict__ rel2,
                                 const void* __restrict__ a_attn, const int* __restrict__ flagp,
                                 float* __restrict__ cvals)
{
    const int f32 = *flagp;
    int t = threadIdx.x;             // 128 threads: wave0 -> rel1, wave1 -> rel2
    const void* r = (t < 64) ? rel1 : rel2;
    int l = t & 63;
    float v = tanhf(ldf(r, l, f32)) * ldf(a_attn, 64 + (l & 31), f32);
    #pragma unroll
    for (int off = 16; off; off >>= 1) v += __shfl_xor(v, off, 32);
    if ((l & 31) == 0) cvals[(t >> 6) * 2 + (l >> 5)] = v;
}

// ---------------- precompute: M = blockdiag(We@Wo) [32x32], c32 = rel@Wo [32] ----------------
__global__ void precompute_kernel(const void* __restrict__ We, const void* __restrict__ Wo,
                                  const void* __restrict__ rel, const int* __restrict__ flagp,
                                  float* __restrict__ M, float* __restrict__ c32)
{
    const int f32 = *flagp;
    int t = threadIdx.x;            // 1024 threads
    int m = t >> 5, j = t & 31;
    int h = m >> 4, c = m & 15;
    float s = 0.f;
    for (int jj = 0; jj < 32; ++jj)
        s += ldf(We, c * 64 + h * 32 + jj, f32) * ldf(Wo, (size_t)(h * 32 + jj) * 32 + j, f32);
    M[m * 32 + j] = s;
    if (t < 32) {
        float s2 = 0.f;
        for (int ch = 0; ch < 64; ++ch)
            s2 += ldf(rel, ch, f32) * ldf(Wo, (size_t)ch * 32 + t, f32);
        c32[t] = s2;
    }
}

// ---------------- edge scores: thread per 2 edges, rolled jb loop (no spills) ----------------
__global__ __launch_bounds__(256) void edge_score_kernel(
    const void* __restrict__ ea, const void* __restrict__ We,
    const int* __restrict__ row, const int* __restrict__ col,
    const float* __restrict__ sq_dst, const float* __restrict__ sk_src,
    const float* __restrict__ cvals, const void* __restrict__ a_attn,
    const int* __restrict__ flagp,
    float* __restrict__ ex_out, int num_e)
{
    const int f32 = *flagp;
    __shared__ float We_s[16 * 64];
    __shared__ float a3_s[32];
    __shared__ float c_s[2];
    for (int i = threadIdx.x; i < 16 * 64; i += 256) We_s[i] = ldf(We, i, f32);
    if (threadIdx.x < 32) a3_s[threadIdx.x] = ldf(a_attn, 96 + threadIdx.x, f32);
    if (threadIdx.x < 2)  c_s[threadIdx.x]  = cvals[threadIdx.x];
    __syncthreads();

    const int e0 = blockIdx.x * 512 + threadIdx.x;
    const int e1 = e0 + 256;
    const bool v1 = (e1 < num_e);
    if (e0 >= num_e) return;

    float er0[16], er1[16];
    load_ea16(ea, (size_t)e0, f32, er0);
    if (v1) load_ea16(ea, (size_t)e1, f32, er1);
    else {
        #pragma unroll
        for (int c = 0; c < 16; ++c) er1[c] = 0.f;
    }

    float acc00 = 0.f, acc01 = 0.f, acc10 = 0.f, acc11 = 0.f;
    #pragma unroll 1                       // keep rolled: avoids VGPR blowup/spills
    for (int jb = 0; jb < 64; jb += 16) {
        float t0[16], t1[16];
        #pragma unroll
        for (int jj = 0; jj < 16; ++jj) { t0[jj] = 0.f; t1[jj] = 0.f; }
        #pragma unroll
        for (int c = 0; c < 16; ++c) {
            #pragma unroll
            for (int jj = 0; jj < 16; ++jj) {
                float w = We_s[c * 64 + jb + jj];   // uniform broadcast
                t0[jj] += er0[c] * w;
                t1[jj] += er1[c] * w;
            }
        }
        float p0 = 0.f, p1 = 0.f;
        #pragma unroll
        for (int jj = 0; jj < 16; ++jj) {
            float a = a3_s[(jb + jj) & 31];
            p0 += fast_tanh(t0[jj]) * a;
            p1 += fast_tanh(t1[jj]) * a;
        }
        if (jb & 32) { acc01 += p0; acc11 += p1; }
        else         { acc00 += p0; acc10 += p1; }
    }

    {
        int d = col[e0], s = row[e0];
        float2 sqd = ((const float2*)sq_dst)[d];
        float2 sks = ((const float2*)sk_src)[s];
        float s0 = fminf(30.f, fmaxf(-30.f, acc00 + sqd.x + sks.x + c_s[0]));
        float s1 = fminf(30.f, fmaxf(-30.f, acc01 + sqd.y + sks.y + c_s[1]));
        ((float2*)ex_out)[e0] = make_float2(__expf(s0), __expf(s1));
    }
    if (v1) {
        int d = col[e1], s = row[e1];
        float2 sqd = ((const float2*)sq_dst)[d];
        float2 sks = ((const float2*)sk_src)[s];
        float s0 = fminf(30.f, fmaxf(-30.f, acc10 + sqd.x + sks.x + c_s[0]));
        float s1 = fminf(30.f, fmaxf(-30.f, acc11 + sqd.y + sks.y + c_s[1]));
        ((float2*)ex_out)[e1] = make_float2(__expf(s0), __expf(s1));
    }
}

// ---------------- CSR build ----------------
__global__ __launch_bounds__(256) void hist_kernel(const int* __restrict__ col,
                                                   int* __restrict__ cnt, int rb, int num_e)
{
    int e = blockIdx.x * 256 + threadIdx.x;
    if (e < num_e) atomicAdd(&cnt[rb + col[e]], 1);
}

__global__ __launch_bounds__(256) void scan1_kernel(const int* __restrict__ cnt,
                                                    int* __restrict__ partial, int n)
{
    __shared__ int wsum[4];
    int t = threadIdx.x;
    int i0 = blockIdx.x * 512 + 2 * t;
    int s = ((i0 < n) ? cnt[i0] : 0) + ((i0 + 1 < n) ? cnt[i0 + 1] : 0);
    #pragma unroll
    for (int o = 32; o; o >>= 1) s += __shfl_xor(s, o, 64);
    if ((t & 63) == 0) wsum[t >> 6] = s;
    __syncthreads();
    if (t == 0) partial[blockIdx.x] = wsum[0] + wsum[1] + wsum[2] + wsum[3];
}

__global__ void scan2_kernel(const int* __restrict__ partial, int* __restrict__ pp,
                             int* __restrict__ off, int nch, int noff)
{
    int lane = threadIdx.x;   // 64 threads
    int running = 0;
    for (int base = 0; base < nch; base += 64) {
        int i = base + lane;
        int o = (i < nch) ? partial[i] : 0;
        int v = o;
        #pragma unroll
        for (int d = 1; d < 64; d <<= 1) {
            int u = __shfl_up(v, d, 64);
            if (lane >= d) v += u;
        }
        if (i < nch) pp[i] = running + v - o;
        running += __shfl(v, 63, 64);
    }
    if (lane == 0) off[noff] = running;
}

__global__ __launch_bounds__(256) void scan3_kernel(const int* __restrict__ cnt,
                                                    const int* __restrict__ pp,
                                                    int* __restrict__ off,
                                                    int* __restrict__ cursor, int n)
{
    __shared__ int tmp[256];
    int t = threadIdx.x;
    int i0 = blockIdx.x * 512 + 2 * t;
    int v0 = (i0 < n) ? cnt[i0] : 0;
    int v1 = (i0 + 1 < n) ? cnt[i0 + 1] : 0;
    int pair = v0 + v1;
    tmp[t] = pair;
    __syncthreads();
    for (int d = 1; d < 256; d <<= 1) {
        int x = (t >= d) ? tmp[t - d] : 0;
        __syncthreads();
        tmp[t] += x;
        __syncthreads();
    }
    int excl = tmp[t] - pair + pp[blockIdx.x];
    if (i0 < n)     { off[i0] = excl;          cursor[i0] = excl; }
    if (i0 + 1 < n) { off[i0 + 1] = excl + v0; cursor[i0 + 1] = excl + v0; }
}

__global__ __launch_bounds__(256) void scatter_kernel(
    const int* __restrict__ row, const int* __restrict__ col,
    const float2* __restrict__ ex, int* __restrict__ cursor,
    uint4* __restrict__ payload, int rb, int num_e)
{
    int e = blockIdx.x * 256 + threadIdx.x;
    if (e >= num_e) return;
    int pos = atomicAdd(&cursor[rb + col[e]], 1);
    float2 x2 = ex[e];
    payload[pos] = make_uint4((unsigned)row[e], __float_as_uint(x2.x),
                              __float_as_uint(x2.y), (unsigned)e);
}

// ---------------- fused aggregation + output projection (CSR, no atomics) ----------------
__global__ __launch_bounds__(256) void agg_final_kernel(
    const uint4* __restrict__ payload, const int* __restrict__ off,
    const float* __restrict__ v_src, const void* __restrict__ x,
    const void* __restrict__ ea, const void* __restrict__ Wo,
    const void* __restrict__ bo, const void* __restrict__ Wr,
    const float* __restrict__ M, const float* __restrict__ c32,
    const int* __restrict__ flagp, void* __restrict__ out,
    size_t out_elem_off, int relbase, int n_nodes)
{
    const int f32  = *flagp;
    const int lane = threadIdx.x & 63;
    const int wv   = threadIdx.x >> 6;
    const int j    = lane & 31;
    const int half = lane >> 5;

    __shared__ float stage[4][160];   // per-wave: y[64] | x[64] | u[32]

    float WoR[32], WrR[32], MR[16];
    const int cb = half * 32;
    #pragma unroll
    for (int cc = 0; cc < 32; ++cc) {
        WoR[cc] = ldf(Wo, (size_t)(cb + cc) * 32 + j, f32);
        WrR[cc] = ldf(Wr, (size_t)(cb + cc) * 32 + j, f32);
    }
    const int ub = half * 16;
    #pragma unroll
    for (int cc = 0; cc < 16; ++cc) MR[cc] = M[(ub + cc) * 32 + j];
    const float boR  = ldf(bo, j, f32);
    const float c32R = c32[j];

    const int stride = gridDim.x * 4;
    const int iters  = (n_nodes + stride - 1) / stride;
    int d = blockIdx.x * 4 + wv;

    for (int it = 0; it < iters; ++it, d += stride) {
        const bool valid = (d < n_nodes);
        const int dd  = valid ? d : (n_nodes - 1);
        const int idx = relbase + dd;
        const int b   = __builtin_amdgcn_readfirstlane(off[idx]);
        const int en  = __builtin_amdgcn_readfirstlane(off[idx + 1]);
        const int deg = en - b;

        float den0 = 0.f, den1 = 0.f;
        #pragma unroll 4
        for (int k = b; k < en; ++k) {
            uint4 p = payload[k];
            den0 += __uint_as_float(p.y);
            den1 += __uint_as_float(p.z);
        }
        float inv0 = (deg > 0) ? __builtin_amdgcn_rcpf(den0) : 0.f;
        float inv1 = (deg > 0) ? __builtin_amdgcn_rcpf(den1) : 0.f;
        const float invh = (lane < 32) ? inv0 : inv1;

        float y = 0.f, uacc = 0.f;
        const int c16 = lane & 15;
        #pragma unroll 2
        for (int k = b; k < en; ++k) {
            uint4 p = payload[k];
            float exh = (lane < 32) ? __uint_as_float(p.y) : __uint_as_float(p.z);
            float w = exh * invh;
            float vv = v_src[(size_t)p.x * 64 + lane];
            y = fmaf(w, vv, y);
            float eav = ldf(ea, (size_t)p.w * 16 + c16, f32);
            uacc = fmaf(w, eav, uacc);
        }

        float xv = ldf(x, (size_t)dd * 64 + lane, f32);

        float* st = stage[wv];
        st[lane] = y;
        st[64 + lane] = xv;
        if ((lane & 31) < 16) st[128 + half * 16 + c16] = uacc;
        __syncthreads();

        float acc = 0.f;
        #pragma unroll
        for (int cc = 0; cc < 32; ++cc) {
            acc = fmaf(st[cb + cc], WoR[cc], acc);
            acc = fmaf(st[64 + cb + cc], WrR[cc], acc);
        }
        #pragma unroll
        for (int cc = 0; cc < 16; ++cc)
            acc = fmaf(st[128 + ub + cc], MR[cc], acc);

        float other = __shfl(acc, lane ^ 32, 64);
        if (valid && lane < 32) {
            float o = acc + other + boR + ((deg > 0) ? c32R : 0.f);
            stf(out, out_elem_off + (size_t)dd * 32 + j, f32, o);
        }
        __syncthreads();
    }
}

extern "C" void kernel_launch(void* const* d_in, const int* in_sizes, int n_in,
                              void* d_out, int out_size, void* d_ws, size_t ws_size,
                              hipStream_t stream)
{
    const void* x_a   = d_in[0];
    const void* x_b   = d_in[1];
    const void* ea1   = d_in[2];
    const void* ea2   = d_in[3];
    const void* Wq_a  = d_in[4];
    const void* Wk_a  = d_in[5];
    const void* Wv_a  = d_in[6];
    const void* Wq_b  = d_in[7];
    const void* Wk_b  = d_in[8];
    const void* Wv_b  = d_in[9];
    const void* emb_a = d_in[10];
    const void* emb_b = d_in[11];
    const void* rel1  = d_in[12];
    const void* rel2  = d_in[13];
    const void* We    = d_in[14];
    const void* a_at  = d_in[15];
    const void* Wo_a  = d_in[16];
    const void* bo_a  = d_in[17];
    const void* Wo_b  = d_in[18];
    const void* bo_b  = d_in[19];
    const void* Wr_a  = d_in[20];
    const void* Wr_b  = d_in[21];
    const int*  row1  = (const int*)d_in[22];
    const int*  col1  = (const int*)d_in[23];
    const int*  row2  = (const int*)d_in[24];
    const int*  col2  = (const int*)d_in[25];

    const int N = in_sizes[0] / 64;   // nodes per type
    const int E = in_sizes[22];       // edges per relation

    // ---- workspace layout ----
    float* ws = (float*)d_ws;
    size_t off = 0;
    int*   flag = (int*)ws;        off += 64;
    float* v_a  = ws + off;        off += (size_t)N * 64;
    float* v_b  = ws + off;        off += (size_t)N * 64;
    float* sq_a = ws + off;        off += (size_t)N * 2;
    float* sk_a = ws + off;        off += (size_t)N * 2;
    float* sq_b = ws + off;        off += (size_t)N * 2;
    float* sk_b = ws + off;        off += (size_t)N * 2;
    float* cvals = ws + off;       off += 4;
    float* ex1  = ws + off;        off += (size_t)E * 2;
    float* ex2  = ws + off;        off += (size_t)E * 2;
    float* M1   = ws + off;        off += 1024;
    float* c321 = ws + off;        off += 32;
    float* M2   = ws + off;        off += 1024;
    float* c322 = ws + off;        off += 32;
    int*   cnt    = (int*)(ws + off);  off += (size_t)2 * N;
    int*   offs   = (int*)(ws + off);  off += (size_t)2 * N + 2;
    int*   cursor = (int*)(ws + off);  off += (size_t)2 * N;
    int*   partial = (int*)(ws + off); off += 512;
    int*   pp      = (int*)(ws + off); off += 512;
    off = (off + 3) & ~(size_t)3;     // 16B align for uint4
    uint4* payload = (uint4*)(ws + off); off += (size_t)2 * E * 4;

    const int node_blocks  = 256;                       // grid-stride MFMA tiles
    const int score_blocks = (E + 511) / 512;
    const int eb_blocks    = (E + 255) / 256;
    const int nch          = (2 * N + 511) / 512;
    const int agg_blocks   = 2048;

    detect_kernel<<<1, 128, 0, stream>>>((const unsigned short*)a_at, flag);
    hipMemsetAsync(cnt, 0, (size_t)2 * N * sizeof(int), stream);

    node_prep_kernel<<<node_blocks, 256, 0, stream>>>(x_a, Wq_a, Wk_a, Wv_a, emb_a, a_at, flag, v_a, sq_a, sk_a, N);
    node_prep_kernel<<<node_blocks, 256, 0, stream>>>(x_b, Wq_b, Wk_b, Wv_b, emb_b, a_at, flag, v_b, sq_b, sk_b, N);
    rel_const_kernel<<<1, 128, 0, stream>>>(rel1, rel2, a_at, flag, cvals);
    precompute_kernel<<<1, 1024, 0, stream>>>(We, Wo_b, rel1, flag, M1, c321);  // rel1 -> out_b
    precompute_kernel<<<1, 1024, 0, stream>>>(We, Wo_a, rel2, flag, M2, c322);  // rel2 -> out_a

    hist_kernel<<<eb_blocks, 256, 0, stream>>>(col1, cnt, 0, E);
    hist_kernel<<<eb_blocks, 256, 0, stream>>>(col2, cnt, N, E);
    scan1_kernel<<<nch, 256, 0, stream>>>(cnt, partial, 2 * N);
    scan2_kernel<<<1, 64, 0, stream>>>(partial, pp, offs, nch, 2 * N);
    scan3_kernel<<<nch, 256, 0, stream>>>(cnt, pp, offs, cursor, 2 * N);

    edge_score_kernel<<<score_blocks, 256, 0, stream>>>(ea1, We, row1, col1, sq_b, sk_a, cvals + 0, a_at, flag, ex1, E);
    edge_score_kernel<<<score_blocks, 256, 0, stream>>>(ea2, We, row2, col2, sq_a, sk_b, cvals + 2, a_at, flag, ex2, E);

    scatter_kernel<<<eb_blocks, 256, 0, stream>>>(row1, col1, (const float2*)ex1, cursor, payload, 0, E);
    scatter_kernel<<<eb_blocks, 256, 0, stream>>>(row2, col2, (const float2*)ex2, cursor, payload, N, E);

    // rel1: src a -> dst b (out_b at element offset N*32); rel2: src b -> dst a
    agg_final_kernel<<<agg_blocks, 256, 0, stream>>>(payload, offs, v_a, x_b, ea1, Wo_b, bo_b, Wr_b,
                                                     M1, c321, flag, d_out, (size_t)N * 32, 0, N);
    agg_final_kernel<<<agg_blocks, 256, 0, stream>>>(payload, offs, v_b, x_a, ea2, Wo_a, bo_a, Wr_a,
                                                     M2, c322, flag, d_out, 0, N, N);
}

// Round 6
// 918.073 us; speedup vs baseline: 3.1016x; 1.0402x over previous
//
#include <hip/hip_runtime.h>
#include <hip/hip_bf16.h>

typedef __hip_bfloat16 bf16;
typedef __attribute__((ext_vector_type(8))) short short8;
typedef __attribute__((ext_vector_type(4))) float float4v;

static __device__ __forceinline__ float b2f(bf16 x) { return __bfloat162float(x); }

// dtype-dispatched load/store: f32=1 -> buffer is float32, f32=0 -> bfloat16.
static __device__ __forceinline__ float ldf(const void* p, size_t i, int f32) {
    return f32 ? ((const float*)p)[i] : b2f(((const bf16*)p)[i]);
}
static __device__ __forceinline__ void stf(void* p, size_t i, int f32, float v) {
    if (f32) ((float*)p)[i] = v;
    else     ((bf16*)p)[i] = __float2bfloat16(v);
}

// fast tanh: 1 - 2/(e^2x + 1)
static __device__ __forceinline__ float fast_tanh(float x) {
    float t = __expf(2.f * x);
    return 1.f - 2.f * __builtin_amdgcn_rcpf(t + 1.f);
}

// load 16 edge-attr channels of edge e into registers (either dtype)
static __device__ __forceinline__ void load_ea16(const void* ea, size_t e, int f32, float* er) {
    if (f32) {
        const float4* p = (const float4*)((const float*)ea + e * 16);
        #pragma unroll
        for (int q = 0; q < 4; ++q) {
            float4 v = p[q];
            er[4*q] = v.x; er[4*q+1] = v.y; er[4*q+2] = v.z; er[4*q+3] = v.w;
        }
    } else {
        const uint4* p = (const uint4*)((const bf16*)ea + e * 16);
        #pragma unroll
        for (int q = 0; q < 2; ++q) {
            uint4 u = p[q];
            er[8*q+0] = __uint_as_float(u.x << 16);
            er[8*q+1] = __uint_as_float(u.x & 0xffff0000u);
            er[8*q+2] = __uint_as_float(u.y << 16);
            er[8*q+3] = __uint_as_float(u.y & 0xffff0000u);
            er[8*q+4] = __uint_as_float(u.z << 16);
            er[8*q+5] = __uint_as_float(u.z & 0xffff0000u);
            er[8*q+6] = __uint_as_float(u.w << 16);
            er[8*q+7] = __uint_as_float(u.w & 0xffff0000u);
        }
    }
}

// ---------------- dtype detector ----------------
__global__ void detect_kernel(const unsigned short* __restrict__ a, int* __restrict__ flag)
{
    __shared__ int cnt;
    if (threadIdx.x == 0) cnt = 0;
    __syncthreads();
    unsigned e = (a[threadIdx.x] >> 7) & 0xFF;
    if (e < 100 || e > 133) atomicAdd(&cnt, 1);
    __syncthreads();
    if (threadIdx.x == 0) *flag = (cnt >= 16) ? 1 : 0;   // 1 => float32 tensors
}

// ---------------- W transpose (bf16 only): wt[m][j*64+c] = W_m[c*64+j] ----------------
__global__ __launch_bounds__(256) void transpose_w_kernel(
    const unsigned short* __restrict__ W0, const unsigned short* __restrict__ W1,
    const unsigned short* __restrict__ W2, const unsigned short* __restrict__ W3,
    const unsigned short* __restrict__ W4, const unsigned short* __restrict__ W5,
    const int* __restrict__ flagp, unsigned short* __restrict__ wt)
{
    if (*flagp) return;
    const unsigned short* src;
    switch (blockIdx.x) {
        case 0: src = W0; break; case 1: src = W1; break; case 2: src = W2; break;
        case 3: src = W3; break; case 4: src = W4; break; default: src = W5; break;
    }
    unsigned short* dst = wt + blockIdx.x * 4096;
    for (int i = threadIdx.x; i < 4096; i += 256) {
        int c = i >> 6, j = i & 63;
        dst[j * 64 + c] = src[c * 64 + j];
    }
}

// ---------------- node prep, bf16 MFMA path: one 16-node tile per wave ----------------
// Handles BOTH node types in one launch: waves [0, tiles) -> type a,
// [tiles, 2*tiles) -> type b. Zero LDS. Fragments from transposed W (contig k).
__global__ __launch_bounds__(256) void node_prep_mfma_kernel(
    const void* __restrict__ x_a, const void* __restrict__ x_b,
    const unsigned short* __restrict__ wt,
    const void* __restrict__ emb_a, const void* __restrict__ emb_b,
    const void* __restrict__ a_attn, const int* __restrict__ flagp,
    float* __restrict__ v_a, float* __restrict__ v_b,
    float* __restrict__ sq_a, float* __restrict__ sk_a,
    float* __restrict__ sq_b, float* __restrict__ sk_b,
    int n_nodes, int tiles)
{
    if (*flagp) return;
    const int wave_id = blockIdx.x * 4 + (threadIdx.x >> 6);
    if (wave_id >= 2 * tiles) return;
    const int type = (wave_id >= tiles);
    const int tile = type ? (wave_id - tiles) : wave_id;

    const unsigned short* xp = (const unsigned short*)(type ? x_b : x_a);
    const unsigned short* wq = wt + (type ? 3 * 4096 : 0);
    const unsigned short* wk = wq + 4096;
    const unsigned short* wv = wk + 4096;
    const bf16* embp = (const bf16*)(type ? emb_b : emb_a);
    const bf16* ap   = (const bf16*)a_attn;
    float*  v_out  = type ? v_b : v_a;
    float2* sq_out = (float2*)(type ? sq_b : sq_a);
    float2* sk_out = (float2*)(type ? sk_b : sk_a);

    const int lane = threadIdx.x & 63;
    const int ml   = lane & 15;        // node-row (A) / out-col (B,D)
    const int g    = lane >> 4;        // quad
    const int g8   = g * 8;

    // per-lane epilogue constants
    float embc[4], acq[4], ack[4];
    #pragma unroll
    for (int t = 0; t < 4; ++t) {
        int colt = t * 16 + ml;
        embc[t] = b2f(embp[colt]);
        acq[t]  = b2f(ap[colt & 31]);
        ack[t]  = b2f(ap[32 + (colt & 31)]);
    }

    // B fragments from Wt[j][c]: lane needs W[k][n=t*16+ml] for k=kh*32+g8+0..7
    // = Wt[t*16+ml][kh*32+g8 ...] -> one contiguous 16B load each.
    short8 Bq[4][2], Bk[4][2], Bv[4][2];
    #pragma unroll
    for (int t = 0; t < 4; ++t) {
        const int rowo = (t * 16 + ml) * 64;
        #pragma unroll
        for (int kh = 0; kh < 2; ++kh) {
            const int o = rowo + kh * 32 + g8;
            Bq[t][kh] = __builtin_bit_cast(short8, *(const uint4*)(wq + o));
            Bk[t][kh] = __builtin_bit_cast(short8, *(const uint4*)(wk + o));
            Bv[t][kh] = __builtin_bit_cast(short8, *(const uint4*)(wv + o));
        }
    }

    const int n0 = tile << 4;
    int nr = n0 + ml; if (nr > n_nodes - 1) nr = n_nodes - 1;
    const uint4* xr = (const uint4*)(xp + (size_t)nr * 64);
    short8 A0 = __builtin_bit_cast(short8, xr[g]);        // k = 0..31 slice
    short8 A1 = __builtin_bit_cast(short8, xr[4 + g]);    // k = 32..63

    float4v accq[4], acck[4], accv[4];
    #pragma unroll
    for (int t = 0; t < 4; ++t) {
        float4v z = {0.f, 0.f, 0.f, 0.f};
        accq[t] = z; acck[t] = z; accv[t] = z;
    }
    #pragma unroll
    for (int t = 0; t < 4; ++t) {
        accq[t] = __builtin_amdgcn_mfma_f32_16x16x32_bf16(A0, Bq[t][0], accq[t], 0, 0, 0);
        accq[t] = __builtin_amdgcn_mfma_f32_16x16x32_bf16(A1, Bq[t][1], accq[t], 0, 0, 0);
        acck[t] = __builtin_amdgcn_mfma_f32_16x16x32_bf16(A0, Bk[t][0], acck[t], 0, 0, 0);
        acck[t] = __builtin_amdgcn_mfma_f32_16x16x32_bf16(A1, Bk[t][1], acck[t], 0, 0, 0);
        accv[t] = __builtin_amdgcn_mfma_f32_16x16x32_bf16(A0, Bv[t][0], accv[t], 0, 0, 0);
        accv[t] = __builtin_amdgcn_mfma_f32_16x16x32_bf16(A1, Bv[t][1], accv[t], 0, 0, 0);
    }

    // v store: D col = t*16+ml, node = n0 + g*4 + r
    #pragma unroll
    for (int t = 0; t < 4; ++t) {
        #pragma unroll
        for (int r = 0; r < 4; ++r) {
            int node = n0 + g * 4 + r;
            if (node < n_nodes) v_out[(size_t)node * 64 + t * 16 + ml] = accv[t][r];
        }
    }

    // score scalars: per node, sum over cols of tanh(q+emb)*a, head-split
    #pragma unroll
    for (int r = 0; r < 4; ++r) {
        float q0 = fast_tanh(accq[0][r] + embc[0]) * acq[0]
                 + fast_tanh(accq[1][r] + embc[1]) * acq[1];
        float q1 = fast_tanh(accq[2][r] + embc[2]) * acq[2]
                 + fast_tanh(accq[3][r] + embc[3]) * acq[3];
        float k0 = fast_tanh(acck[0][r] + embc[0]) * ack[0]
                 + fast_tanh(acck[1][r] + embc[1]) * ack[1];
        float k1 = fast_tanh(acck[2][r] + embc[2]) * ack[2]
                 + fast_tanh(acck[3][r] + embc[3]) * ack[3];
        #pragma unroll
        for (int o = 1; o < 16; o <<= 1) {
            q0 += __shfl_xor(q0, o, 64); q1 += __shfl_xor(q1, o, 64);
            k0 += __shfl_xor(k0, o, 64); k1 += __shfl_xor(k1, o, 64);
        }
        int node = n0 + g * 4 + r;
        if (ml == 0 && node < n_nodes) {
            sq_out[node] = make_float2(q0, q1);
            sk_out[node] = make_float2(k0, k1);
        }
    }
}

// ---------------- node prep, f32 fallback (early-exit in bf16 mode) ----------------
__global__ __launch_bounds__(256) void node_prep_f32_kernel(
    const void* __restrict__ x, const void* __restrict__ Wq,
    const void* __restrict__ Wk, const void* __restrict__ Wv,
    const void* __restrict__ emb, const void* __restrict__ a_attn,
    const int* __restrict__ flagp,
    float* __restrict__ v_out, float* __restrict__ sq_out, float* __restrict__ sk_out,
    int n_nodes)
{
    if (!*flagp) return;
    __shared__ float Wq_s[64 * 64], Wk_s[64 * 64], Wv_s[64 * 64];
    __shared__ float emb_s[64], a_s[64];
    for (int i = threadIdx.x; i < 64 * 64; i += 256) {
        Wq_s[i] = ldf(Wq, i, 1); Wk_s[i] = ldf(Wk, i, 1); Wv_s[i] = ldf(Wv, i, 1);
    }
    if (threadIdx.x < 64) {
        emb_s[threadIdx.x] = ldf(emb, threadIdx.x, 1);
        a_s[threadIdx.x]   = ldf(a_attn, threadIdx.x, 1);
    }
    __syncthreads();

    const int lane   = threadIdx.x & 63;
    const int wave   = (blockIdx.x * blockDim.x + threadIdx.x) >> 6;
    const int nwaves = (gridDim.x * blockDim.x) >> 6;

    for (int n = wave; n < n_nodes; n += nwaves) {
        float xv = ldf(x, (size_t)n * 64 + lane, 1);
        float q = 0.f, k = 0.f, v = 0.f;
        #pragma unroll
        for (int c = 0; c < 64; ++c) {
            float xc = __shfl(xv, c, 64);
            q += xc * Wq_s[c * 64 + lane];
            k += xc * Wk_s[c * 64 + lane];
            v += xc * Wv_s[c * 64 + lane];
        }
        v_out[(size_t)n * 64 + lane] = v;
        float tq = fast_tanh(q + emb_s[lane]) * a_s[lane & 31];
        float tk = fast_tanh(k + emb_s[lane]) * a_s[32 + (lane & 31)];
        #pragma unroll
        for (int off = 16; off; off >>= 1) {
            tq += __shfl_xor(tq, off, 32);
            tk += __shfl_xor(tk, off, 32);
        }
        if ((lane & 31) == 0) {
            int h = lane >> 5;
            sq_out[n * 2 + h] = tq;
            sk_out[n * 2 + h] = tk;
        }
    }
}

// ---------------- relation constants: c[h] = sum_j tanh(rel[h,j]) * a[64+j'] ----------------
__global__ void rel_const_kernel(const void* __restrict__ rel1, const void* __restrict__ rel2,
                                 const void* __restrict__ a_attn, const int* __restrict__ flagp,
                                 float* __restrict__ cvals)
{
    const int f32 = *flagp;
    int t = threadIdx.x;             // 128 threads: wave0 -> rel1, wave1 -> rel2
    const void* r = (t < 64) ? rel1 : rel2;
    int l = t & 63;
    float v = tanhf(ldf(r, l, f32)) * ldf(a_attn, 64 + (l & 31), f32);
    #pragma unroll
    for (int off = 16; off; off >>= 1) v += __shfl_xor(v, off, 32);
    if ((l & 31) == 0) cvals[(t >> 6) * 2 + (l >> 5)] = v;
}

// ---------------- precompute: M = blockdiag(We@Wo) [32x32], c32 = rel@Wo [32] ----------------
__global__ void precompute_kernel(const void* __restrict__ We, const void* __restrict__ Wo,
                                  const void* __restrict__ rel, const int* __restrict__ flagp,
                                  float* __restrict__ M, float* __restrict__ c32)
{
    const int f32 = *flagp;
    int t = threadIdx.x;            // 1024 threads
    int m = t >> 5, j = t & 31;
    int h = m >> 4, c = m & 15;
    float s = 0.f;
    for (int jj = 0; jj < 32; ++jj)
        s += ldf(We, c * 64 + h * 32 + jj, f32) * ldf(Wo, (size_t)(h * 32 + jj) * 32 + j, f32);
    M[m * 32 + j] = s;
    if (t < 32) {
        float s2 = 0.f;
        for (int ch = 0; ch < 64; ++ch)
            s2 += ldf(rel, ch, f32) * ldf(Wo, (size_t)ch * 32 + t, f32);
        c32[t] = s2;
    }
}

// ---------------- edge scores: thread per 2 edges, rolled jb loop (no spills) ----------------
__global__ __launch_bounds__(256) void edge_score_kernel(
    const void* __restrict__ ea, const void* __restrict__ We,
    const int* __restrict__ row, const int* __restrict__ col,
    const float* __restrict__ sq_dst, const float* __restrict__ sk_src,
    const float* __restrict__ cvals, const void* __restrict__ a_attn,
    const int* __restrict__ flagp,
    float* __restrict__ ex_out, int num_e)
{
    const int f32 = *flagp;
    __shared__ float We_s[16 * 64];
    __shared__ float a3_s[32];
    __shared__ float c_s[2];
    for (int i = threadIdx.x; i < 16 * 64; i += 256) We_s[i] = ldf(We, i, f32);
    if (threadIdx.x < 32) a3_s[threadIdx.x] = ldf(a_attn, 96 + threadIdx.x, f32);
    if (threadIdx.x < 2)  c_s[threadIdx.x]  = cvals[threadIdx.x];
    __syncthreads();

    const int e0 = blockIdx.x * 512 + threadIdx.x;
    const int e1 = e0 + 256;
    const bool v1 = (e1 < num_e);
    if (e0 >= num_e) return;

    float er0[16], er1[16];
    load_ea16(ea, (size_t)e0, f32, er0);
    if (v1) load_ea16(ea, (size_t)e1, f32, er1);
    else {
        #pragma unroll
        for (int c = 0; c < 16; ++c) er1[c] = 0.f;
    }

    float acc00 = 0.f, acc01 = 0.f, acc10 = 0.f, acc11 = 0.f;
    #pragma unroll 1                       // keep rolled: avoids VGPR blowup/spills
    for (int jb = 0; jb < 64; jb += 16) {
        float t0[16], t1[16];
        #pragma unroll
        for (int jj = 0; jj < 16; ++jj) { t0[jj] = 0.f; t1[jj] = 0.f; }
        #pragma unroll
        for (int c = 0; c < 16; ++c) {
            #pragma unroll
            for (int jj = 0; jj < 16; ++jj) {
                float w = We_s[c * 64 + jb + jj];   // uniform broadcast
                t0[jj] += er0[c] * w;
                t1[jj] += er1[c] * w;
            }
        }
        float p0 = 0.f, p1 = 0.f;
        #pragma unroll
        for (int jj = 0; jj < 16; ++jj) {
            float a = a3_s[(jb + jj) & 31];
            p0 += fast_tanh(t0[jj]) * a;
            p1 += fast_tanh(t1[jj]) * a;
        }
        if (jb & 32) { acc01 += p0; acc11 += p1; }
        else         { acc00 += p0; acc10 += p1; }
    }

    {
        int d = col[e0], s = row[e0];
        float2 sqd = ((const float2*)sq_dst)[d];
        float2 sks = ((const float2*)sk_src)[s];
        float s0 = fminf(30.f, fmaxf(-30.f, acc00 + sqd.x + sks.x + c_s[0]));
        float s1 = fminf(30.f, fmaxf(-30.f, acc01 + sqd.y + sks.y + c_s[1]));
        ((float2*)ex_out)[e0] = make_float2(__expf(s0), __expf(s1));
    }
    if (v1) {
        int d = col[e1], s = row[e1];
        float2 sqd = ((const float2*)sq_dst)[d];
        float2 sks = ((const float2*)sk_src)[s];
        float s0 = fminf(30.f, fmaxf(-30.f, acc10 + sqd.x + sks.x + c_s[0]));
        float s1 = fminf(30.f, fmaxf(-30.f, acc11 + sqd.y + sks.y + c_s[1]));
        ((float2*)ex_out)[e1] = make_float2(__expf(s0), __expf(s1));
    }
}

// ---------------- CSR build ----------------
__global__ __launch_bounds__(256) void hist_kernel(const int* __restrict__ col,
                                                   int* __restrict__ cnt, int rb, int num_e)
{
    int e = blockIdx.x * 256 + threadIdx.x;
    if (e < num_e) atomicAdd(&cnt[rb + col[e]], 1);
}

__global__ __launch_bounds__(256) void scan1_kernel(const int* __restrict__ cnt,
                                                    int* __restrict__ partial, int n)
{
    __shared__ int wsum[4];
    int t = threadIdx.x;
    int i0 = blockIdx.x * 512 + 2 * t;
    int s = ((i0 < n) ? cnt[i0] : 0) + ((i0 + 1 < n) ? cnt[i0 + 1] : 0);
    #pragma unroll
    for (int o = 32; o; o >>= 1) s += __shfl_xor(s, o, 64);
    if ((t & 63) == 0) wsum[t >> 6] = s;
    __syncthreads();
    if (t == 0) partial[blockIdx.x] = wsum[0] + wsum[1] + wsum[2] + wsum[3];
}

__global__ void scan2_kernel(const int* __restrict__ partial, int* __restrict__ pp,
                             int* __restrict__ off, int nch, int noff)
{
    int lane = threadIdx.x;   // 64 threads
    int running = 0;
    for (int base = 0; base < nch; base += 64) {
        int i = base + lane;
        int o = (i < nch) ? partial[i] : 0;
        int v = o;
        #pragma unroll
        for (int d = 1; d < 64; d <<= 1) {
            int u = __shfl_up(v, d, 64);
            if (lane >= d) v += u;
        }
        if (i < nch) pp[i] = running + v - o;
        running += __shfl(v, 63, 64);
    }
    if (lane == 0) off[noff] = running;
}

__global__ __launch_bounds__(256) void scan3_kernel(const int* __restrict__ cnt,
                                                    const int* __restrict__ pp,
                                                    int* __restrict__ off,
                                                    int* __restrict__ cursor, int n)
{
    __shared__ int tmp[256];
    int t = threadIdx.x;
    int i0 = blockIdx.x * 512 + 2 * t;
    int v0 = (i0 < n) ? cnt[i0] : 0;
    int v1 = (i0 + 1 < n) ? cnt[i0 + 1] : 0;
    int pair = v0 + v1;
    tmp[t] = pair;
    __syncthreads();
    for (int d = 1; d < 256; d <<= 1) {
        int x = (t >= d) ? tmp[t - d] : 0;
        __syncthreads();
        tmp[t] += x;
        __syncthreads();
    }
    int excl = tmp[t] - pair + pp[blockIdx.x];
    if (i0 < n)     { off[i0] = excl;          cursor[i0] = excl; }
    if (i0 + 1 < n) { off[i0 + 1] = excl + v0; cursor[i0 + 1] = excl + v0; }
}

__global__ __launch_bounds__(256) void scatter_kernel(
    const int* __restrict__ row, const int* __restrict__ col,
    const float2* __restrict__ ex, int* __restrict__ cursor,
    uint4* __restrict__ payload, int rb, int num_e)
{
    int e = blockIdx.x * 256 + threadIdx.x;
    if (e >= num_e) return;
    int pos = atomicAdd(&cursor[rb + col[e]], 1);
    float2 x2 = ex[e];
    payload[pos] = make_uint4((unsigned)row[e], __float_as_uint(x2.x),
                              __float_as_uint(x2.y), (unsigned)e);
}

// ---------------- fused aggregation + output projection (CSR, no atomics) ----------------
__global__ __launch_bounds__(256) void agg_final_kernel(
    const uint4* __restrict__ payload, const int* __restrict__ off,
    const float* __restrict__ v_src, const void* __restrict__ x,
    const void* __restrict__ ea, const void* __restrict__ Wo,
    const void* __restrict__ bo, const void* __restrict__ Wr,
    const float* __restrict__ M, const float* __restrict__ c32,
    const int* __restrict__ flagp, void* __restrict__ out,
    size_t out_elem_off, int relbase, int n_nodes)
{
    const int f32  = *flagp;
    const int lane = threadIdx.x & 63;
    const int wv   = threadIdx.x >> 6;
    const int j    = lane & 31;
    const int half = lane >> 5;

    __shared__ float stage[4][160];   // per-wave: y[64] | x[64] | u[32]

    float WoR[32], WrR[32], MR[16];
    const int cb = half * 32;
    #pragma unroll
    for (int cc = 0; cc < 32; ++cc) {
        WoR[cc] = ldf(Wo, (size_t)(cb + cc) * 32 + j, f32);
        WrR[cc] = ldf(Wr, (size_t)(cb + cc) * 32 + j, f32);
    }
    const int ub = half * 16;
    #pragma unroll
    for (int cc = 0; cc < 16; ++cc) MR[cc] = M[(ub + cc) * 32 + j];
    const float boR  = ldf(bo, j, f32);
    const float c32R = c32[j];

    const int stride = gridDim.x * 4;
    const int iters  = (n_nodes + stride - 1) / stride;
    int d = blockIdx.x * 4 + wv;

    for (int it = 0; it < iters; ++it, d += stride) {
        const bool valid = (d < n_nodes);
        const int dd  = valid ? d : (n_nodes - 1);
        const int idx = relbase + dd;
        const int b   = __builtin_amdgcn_readfirstlane(off[idx]);
        const int en  = __builtin_amdgcn_readfirstlane(off[idx + 1]);
        const int deg = en - b;

        float den0 = 0.f, den1 = 0.f;
        #pragma unroll 4
        for (int k = b; k < en; ++k) {
            uint4 p = payload[k];
            den0 += __uint_as_float(p.y);
            den1 += __uint_as_float(p.z);
        }
        float inv0 = (deg > 0) ? __builtin_amdgcn_rcpf(den0) : 0.f;
        float inv1 = (deg > 0) ? __builtin_amdgcn_rcpf(den1) : 0.f;
        const float invh = (lane < 32) ? inv0 : inv1;

        float y = 0.f, uacc = 0.f;
        const int c16 = lane & 15;
        #pragma unroll 2
        for (int k = b; k < en; ++k) {
            uint4 p = payload[k];
            float exh = (lane < 32) ? __uint_as_float(p.y) : __uint_as_float(p.z);
            float w = exh * invh;
            float vv = v_src[(size_t)p.x * 64 + lane];
            y = fmaf(w, vv, y);
            float eav = ldf(ea, (size_t)p.w * 16 + c16, f32);
            uacc = fmaf(w, eav, uacc);
        }

        float xv = ldf(x, (size_t)dd * 64 + lane, f32);

        float* st = stage[wv];
        st[lane] = y;
        st[64 + lane] = xv;
        if ((lane & 31) < 16) st[128 + half * 16 + c16] = uacc;
        __syncthreads();

        float acc = 0.f;
        #pragma unroll
        for (int cc = 0; cc < 32; ++cc) {
            acc = fmaf(st[cb + cc], WoR[cc], acc);
            acc = fmaf(st[64 + cb + cc], WrR[cc], acc);
        }
        #pragma unroll
        for (int cc = 0; cc < 16; ++cc)
            acc = fmaf(st[128 + ub + cc], MR[cc], acc);

        float other = __shfl(acc, lane ^ 32, 64);
        if (valid && lane < 32) {
            float o = acc + other + boR + ((deg > 0) ? c32R : 0.f);
            stf(out, out_elem_off + (size_t)dd * 32 + j, f32, o);
        }
        __syncthreads();
    }
}

extern "C" void kernel_launch(void* const* d_in, const int* in_sizes, int n_in,
                              void* d_out, int out_size, void* d_ws, size_t ws_size,
                              hipStream_t stream)
{
    const void* x_a   = d_in[0];
    const void* x_b   = d_in[1];
    const void* ea1   = d_in[2];
    const void* ea2   = d_in[3];
    const void* Wq_a  = d_in[4];
    const void* Wk_a  = d_in[5];
    const void* Wv_a  = d_in[6];
    const void* Wq_b  = d_in[7];
    const void* Wk_b  = d_in[8];
    const void* Wv_b  = d_in[9];
    const void* emb_a = d_in[10];
    const void* emb_b = d_in[11];
    const void* rel1  = d_in[12];
    const void* rel2  = d_in[13];
    const void* We    = d_in[14];
    const void* a_at  = d_in[15];
    const void* Wo_a  = d_in[16];
    const void* bo_a  = d_in[17];
    const void* Wo_b  = d_in[18];
    const void* bo_b  = d_in[19];
    const void* Wr_a  = d_in[20];
    const void* Wr_b  = d_in[21];
    const int*  row1  = (const int*)d_in[22];
    const int*  col1  = (const int*)d_in[23];
    const int*  row2  = (const int*)d_in[24];
    const int*  col2  = (const int*)d_in[25];

    const int N = in_sizes[0] / 64;   // nodes per type
    const int E = in_sizes[22];       // edges per relation

    // ---- workspace layout ----
    float* ws = (float*)d_ws;
    size_t off = 0;
    int*   flag = (int*)ws;        off += 64;
    float* v_a  = ws + off;        off += (size_t)N * 64;
    float* v_b  = ws + off;        off += (size_t)N * 64;
    float* sq_a = ws + off;        off += (size_t)N * 2;
    float* sk_a = ws + off;        off += (size_t)N * 2;
    float* sq_b = ws + off;        off += (size_t)N * 2;
    float* sk_b = ws + off;        off += (size_t)N * 2;
    float* cvals = ws + off;       off += 4;
    off = (off + 3) & ~(size_t)3;  // 16B align
    unsigned short* wt = (unsigned short*)(ws + off); off += 6 * 4096 / 2;  // 6 transposed 64x64 bf16
    float* ex1  = ws + off;        off += (size_t)E * 2;
    float* ex2  = ws + off;        off += (size_t)E * 2;
    float* M1   = ws + off;        off += 1024;
    float* c321 = ws + off;        off += 32;
    float* M2   = ws + off;        off += 1024;
    float* c322 = ws + off;        off += 32;
    int*   cnt    = (int*)(ws + off);  off += (size_t)2 * N;
    int*   offs   = (int*)(ws + off);  off += (size_t)2 * N + 2;
    int*   cursor = (int*)(ws + off);  off += (size_t)2 * N;
    int*   partial = (int*)(ws + off); off += 512;
    int*   pp      = (int*)(ws + off); off += 512;
    off = (off + 3) & ~(size_t)3;     // 16B align for uint4
    uint4* payload = (uint4*)(ws + off); off += (size_t)2 * E * 4;

    const int tiles        = (N + 15) >> 4;
    const int mfma_blocks  = (2 * tiles + 3) / 4;       // one tile per wave, both types
    const int f32_blocks   = (N * 64 + 255) / 256;
    const int score_blocks = (E + 511) / 512;
    const int eb_blocks    = (E + 255) / 256;
    const int nch          = (2 * N + 511) / 512;
    const int agg_blocks   = 2048;

    detect_kernel<<<1, 128, 0, stream>>>((const unsigned short*)a_at, flag);
    hipMemsetAsync(cnt, 0, (size_t)2 * N * sizeof(int), stream);

    transpose_w_kernel<<<6, 256, 0, stream>>>(
        (const unsigned short*)Wq_a, (const unsigned short*)Wk_a, (const unsigned short*)Wv_a,
        (const unsigned short*)Wq_b, (const unsigned short*)Wk_b, (const unsigned short*)Wv_b,
        flag, wt);
    node_prep_mfma_kernel<<<mfma_blocks, 256, 0, stream>>>(
        x_a, x_b, wt, emb_a, emb_b, a_at, flag,
        v_a, v_b, sq_a, sk_a, sq_b, sk_b, N, tiles);
    node_prep_f32_kernel<<<f32_blocks, 256, 0, stream>>>(x_a, Wq_a, Wk_a, Wv_a, emb_a, a_at, flag, v_a, sq_a, sk_a, N);
    node_prep_f32_kernel<<<f32_blocks, 256, 0, stream>>>(x_b, Wq_b, Wk_b, Wv_b, emb_b, a_at, flag, v_b, sq_b, sk_b, N);

    rel_const_kernel<<<1, 128, 0, stream>>>(rel1, rel2, a_at, flag, cvals);
    precompute_kernel<<<1, 1024, 0, stream>>>(We, Wo_b, rel1, flag, M1, c321);  // rel1 -> out_b
    precompute_kernel<<<1, 1024, 0, stream>>>(We, Wo_a, rel2, flag, M2, c322);  // rel2 -> out_a

    hist_kernel<<<eb_blocks, 256, 0, stream>>>(col1, cnt, 0, E);
    hist_kernel<<<eb_blocks, 256, 0, stream>>>(col2, cnt, N, E);
    scan1_kernel<<<nch, 256, 0, stream>>>(cnt, partial, 2 * N);
    scan2_kernel<<<1, 64, 0, stream>>>(partial, pp, offs, nch, 2 * N);
    scan3_kernel<<<nch, 256, 0, stream>>>(cnt, pp, offs, cursor, 2 * N);

    edge_score_kernel<<<score_blocks, 256, 0, stream>>>(ea1, We, row1, col1, sq_b, sk_a, cvals + 0, a_at, flag, ex1, E);
    edge_score_kernel<<<score_blocks, 256, 0, stream>>>(ea2, We, row2, col2, sq_a, sk_b, cvals + 2, a_at, flag, ex2, E);

    scatter_kernel<<<eb_blocks, 256, 0, stream>>>(row1, col1, (const float2*)ex1, cursor, payload, 0, E);
    scatter_kernel<<<eb_blocks, 256, 0, stream>>>(row2, col2, (const float2*)ex2, cursor, payload, N, E);

    // rel1: src a -> dst b (out_b at element offset N*32); rel2: src b -> dst a
    agg_final_kernel<<<agg_blocks, 256, 0, stream>>>(payload, offs, v_a, x_b, ea1, Wo_b, bo_b, Wr_b,
                                                     M1, c321, flag, d_out, (size_t)N * 32, 0, N);
    agg_final_kernel<<<agg_blocks, 256, 0, stream>>>(payload, offs, v_b, x_a, ea2, Wo_a, bo_a, Wr_a,
                                                     M2, c322, flag, d_out, 0, N, N);
}

// Round 7
// 730.494 us; speedup vs baseline: 3.8980x; 1.2568x over previous
//
#include <hip/hip_runtime.h>
#include <hip/hip_bf16.h>

typedef __hip_bfloat16 bf16;
typedef __attribute__((ext_vector_type(8))) short short8;
typedef __attribute__((ext_vector_type(4))) float float4v;

static __device__ __forceinline__ float b2f(bf16 x) { return __bfloat162float(x); }

// dtype-dispatched load/store: f32=1 -> buffer is float32, f32=0 -> bfloat16.
static __device__ __forceinline__ float ldf(const void* p, size_t i, int f32) {
    return f32 ? ((const float*)p)[i] : b2f(((const bf16*)p)[i]);
}
static __device__ __forceinline__ void stf(void* p, size_t i, int f32, float v) {
    if (f32) ((float*)p)[i] = v;
    else     ((bf16*)p)[i] = __float2bfloat16(v);
}
static __device__ __forceinline__ unsigned short f2bf_bits(float f) {
    bf16 h = __float2bfloat16(f);
    return *(unsigned short*)&h;
}

// fast tanh: 1 - 2/(e^2x + 1)
static __device__ __forceinline__ float fast_tanh(float x) {
    float t = __expf(2.f * x);
    return 1.f - 2.f * __builtin_amdgcn_rcpf(t + 1.f);
}

// load 16 edge-attr channels of edge e into registers (either dtype)
static __device__ __forceinline__ void load_ea16(const void* ea, size_t e, int f32, float* er) {
    if (f32) {
        const float4* p = (const float4*)((const float*)ea + e * 16);
        #pragma unroll
        for (int q = 0; q < 4; ++q) {
            float4 v = p[q];
            er[4*q] = v.x; er[4*q+1] = v.y; er[4*q+2] = v.z; er[4*q+3] = v.w;
        }
    } else {
        const uint4* p = (const uint4*)((const bf16*)ea + e * 16);
        #pragma unroll
        for (int q = 0; q < 2; ++q) {
            uint4 u = p[q];
            er[8*q+0] = __uint_as_float(u.x << 16);
            er[8*q+1] = __uint_as_float(u.x & 0xffff0000u);
            er[8*q+2] = __uint_as_float(u.y << 16);
            er[8*q+3] = __uint_as_float(u.y & 0xffff0000u);
            er[8*q+4] = __uint_as_float(u.z << 16);
            er[8*q+5] = __uint_as_float(u.z & 0xffff0000u);
            er[8*q+6] = __uint_as_float(u.w << 16);
            er[8*q+7] = __uint_as_float(u.w & 0xffff0000u);
        }
    }
}

// ---------------- dtype detector ----------------
// f32 data read as u16: even words have random exponent bits -> many implausible.
__global__ void detect_kernel(const unsigned short* __restrict__ a, int* __restrict__ flag)
{
    __shared__ int cnt;
    if (threadIdx.x == 0) cnt = 0;
    __syncthreads();
    unsigned e = (a[threadIdx.x] >> 7) & 0xFF;
    if (e < 100 || e > 133) atomicAdd(&cnt, 1);
    __syncthreads();
    if (threadIdx.x == 0) *flag = (cnt >= 16) ? 1 : 0;   // 1 => float32 tensors
}

// ---------------- x -> bf16 workspace copy (both node types, one launch) ----------------
__global__ __launch_bounds__(256) void convert_x_kernel(
    const void* __restrict__ xa, const void* __restrict__ xb,
    const int* __restrict__ flagp, unsigned short* __restrict__ xc, size_t n_per)
{
    const int f32 = *flagp;
    size_t i = ((size_t)blockIdx.x * 256 + threadIdx.x) * 8;
    if (i >= 2 * n_per) return;
    const void* src = (i < n_per) ? xa : xb;
    size_t o = (i < n_per) ? i : i - n_per;
    unsigned short out[8];
    if (f32) {
        const float4* p = (const float4*)((const float*)src + o);
        float4 v0 = p[0], v1 = p[1];
        out[0] = f2bf_bits(v0.x); out[1] = f2bf_bits(v0.y);
        out[2] = f2bf_bits(v0.z); out[3] = f2bf_bits(v0.w);
        out[4] = f2bf_bits(v1.x); out[5] = f2bf_bits(v1.y);
        out[6] = f2bf_bits(v1.z); out[7] = f2bf_bits(v1.w);
        *(uint4*)(xc + i) = *(const uint4*)out;
    } else {
        *(uint4*)(xc + i) = *(const uint4*)((const unsigned short*)src + o);
    }
}

// ---------------- W transpose+convert: wt[m][j*64+c] = bf16(W_m[c*64+j]) ----------------
__global__ __launch_bounds__(256) void transpose_w_kernel(
    const void* __restrict__ W0, const void* __restrict__ W1,
    const void* __restrict__ W2, const void* __restrict__ W3,
    const void* __restrict__ W4, const void* __restrict__ W5,
    const int* __restrict__ flagp, unsigned short* __restrict__ wt)
{
    const int f32 = *flagp;
    const void* src;
    switch (blockIdx.x) {
        case 0: src = W0; break; case 1: src = W1; break; case 2: src = W2; break;
        case 3: src = W3; break; case 4: src = W4; break; default: src = W5; break;
    }
    unsigned short* dst = wt + blockIdx.x * 4096;
    for (int i = threadIdx.x; i < 4096; i += 256) {
        int c = i >> 6, j = i & 63;
        dst[j * 64 + c] = f2bf_bits(ldf(src, c * 64 + j, f32));
    }
}

// ---------------- node prep (MFMA, always): one 16-node tile per wave ----------------
// waves [0, tiles) -> type a, [tiles, 2*tiles) -> type b. Zero LDS.
__global__ __launch_bounds__(256) void node_prep_mfma_kernel(
    const unsigned short* __restrict__ xc,
    const unsigned short* __restrict__ wt,
    const void* __restrict__ emb_a, const void* __restrict__ emb_b,
    const void* __restrict__ a_attn, const int* __restrict__ flagp,
    float* __restrict__ v_a, float* __restrict__ v_b,
    float* __restrict__ sq_a, float* __restrict__ sk_a,
    float* __restrict__ sq_b, float* __restrict__ sk_b,
    int n_nodes, int tiles)
{
    const int f32 = *flagp;
    const int wave_id = blockIdx.x * 4 + (threadIdx.x >> 6);
    if (wave_id >= 2 * tiles) return;
    const int type = (wave_id >= tiles);
    const int tile = type ? (wave_id - tiles) : wave_id;

    const unsigned short* xp = xc + (type ? (size_t)n_nodes * 64 : 0);
    const unsigned short* wq = wt + (type ? 3 * 4096 : 0);
    const unsigned short* wk = wq + 4096;
    const unsigned short* wv = wk + 4096;
    const void* embp = type ? emb_b : emb_a;
    float*  v_out  = type ? v_b : v_a;
    float2* sq_out = (float2*)(type ? sq_b : sq_a);
    float2* sk_out = (float2*)(type ? sk_b : sk_a);

    const int lane = threadIdx.x & 63;
    const int ml   = lane & 15;        // node-row (A) / out-col (B,D)
    const int g    = lane >> 4;        // quad
    const int g8   = g * 8;

    // per-lane epilogue constants (dtype-dispatched scalar loads)
    float embc[4], acq[4], ack[4];
    #pragma unroll
    for (int t = 0; t < 4; ++t) {
        int colt = t * 16 + ml;
        embc[t] = ldf(embp, colt, f32);
        acq[t]  = ldf(a_attn, colt & 31, f32);
        ack[t]  = ldf(a_attn, 32 + (colt & 31), f32);
    }

    // B fragments from Wt[n][k]: lane needs W[k=kh*32+g8+j][n=t*16+ml]
    // = wt[(t*16+ml)*64 + kh*32+g8+j] -> one contiguous 16B load each.
    short8 Bq[4][2], Bk[4][2], Bv[4][2];
    #pragma unroll
    for (int t = 0; t < 4; ++t) {
        const int rowo = (t * 16 + ml) * 64;
        #pragma unroll
        for (int kh = 0; kh < 2; ++kh) {
            const int o = rowo + kh * 32 + g8;
            Bq[t][kh] = __builtin_bit_cast(short8, *(const uint4*)(wq + o));
            Bk[t][kh] = __builtin_bit_cast(short8, *(const uint4*)(wk + o));
            Bv[t][kh] = __builtin_bit_cast(short8, *(const uint4*)(wv + o));
        }
    }

    const int n0 = tile << 4;
    int nr = n0 + ml; if (nr > n_nodes - 1) nr = n_nodes - 1;
    const uint4* xr = (const uint4*)(xp + (size_t)nr * 64);
    short8 A0 = __builtin_bit_cast(short8, xr[g]);        // k = 0..31 slice
    short8 A1 = __builtin_bit_cast(short8, xr[4 + g]);    // k = 32..63

    float4v accq[4], acck[4], accv[4];
    #pragma unroll
    for (int t = 0; t < 4; ++t) {
        float4v z = {0.f, 0.f, 0.f, 0.f};
        accq[t] = z; acck[t] = z; accv[t] = z;
    }
    #pragma unroll
    for (int t = 0; t < 4; ++t) {
        accq[t] = __builtin_amdgcn_mfma_f32_16x16x32_bf16(A0, Bq[t][0], accq[t], 0, 0, 0);
        accq[t] = __builtin_amdgcn_mfma_f32_16x16x32_bf16(A1, Bq[t][1], accq[t], 0, 0, 0);
        acck[t] = __builtin_amdgcn_mfma_f32_16x16x32_bf16(A0, Bk[t][0], acck[t], 0, 0, 0);
        acck[t] = __builtin_amdgcn_mfma_f32_16x16x32_bf16(A1, Bk[t][1], acck[t], 0, 0, 0);
        accv[t] = __builtin_amdgcn_mfma_f32_16x16x32_bf16(A0, Bv[t][0], accv[t], 0, 0, 0);
        accv[t] = __builtin_amdgcn_mfma_f32_16x16x32_bf16(A1, Bv[t][1], accv[t], 0, 0, 0);
    }

    // v store: D col = t*16+ml, node = n0 + g*4 + r
    #pragma unroll
    for (int t = 0; t < 4; ++t) {
        #pragma unroll
        for (int r = 0; r < 4; ++r) {
            int node = n0 + g * 4 + r;
            if (node < n_nodes) v_out[(size_t)node * 64 + t * 16 + ml] = accv[t][r];
        }
    }

    // score scalars: per node, sum over cols of tanh(q+emb)*a, head-split (t<2 / t>=2)
    #pragma unroll
    for (int r = 0; r < 4; ++r) {
        float q0 = fast_tanh(accq[0][r] + embc[0]) * acq[0]
                 + fast_tanh(accq[1][r] + embc[1]) * acq[1];
        float q1 = fast_tanh(accq[2][r] + embc[2]) * acq[2]
                 + fast_tanh(accq[3][r] + embc[3]) * acq[3];
        float k0 = fast_tanh(acck[0][r] + embc[0]) * ack[0]
                 + fast_tanh(acck[1][r] + embc[1]) * ack[1];
        float k1 = fast_tanh(acck[2][r] + embc[2]) * ack[2]
                 + fast_tanh(acck[3][r] + embc[3]) * ack[3];
        #pragma unroll
        for (int o = 1; o < 16; o <<= 1) {
            q0 += __shfl_xor(q0, o, 64); q1 += __shfl_xor(q1, o, 64);
            k0 += __shfl_xor(k0, o, 64); k1 += __shfl_xor(k1, o, 64);
        }
        int node = n0 + g * 4 + r;
        if (ml == 0 && node < n_nodes) {
            sq_out[node] = make_float2(q0, q1);
            sk_out[node] = make_float2(k0, k1);
        }
    }
}

// ---------------- relation constants: c[h] = sum_j tanh(rel[h,j]) * a[64+j'] ----------------
__global__ void rel_const_kernel(const void* __restrict__ rel1, const void* __restrict__ rel2,
                                 const void* __restrict__ a_attn, const int* __restrict__ flagp,
                                 float* __restrict__ cvals)
{
    const int f32 = *flagp;
    int t = threadIdx.x;             // 128 threads: wave0 -> rel1, wave1 -> rel2
    const void* r = (t < 64) ? rel1 : rel2;
    int l = t & 63;
    float v = tanhf(ldf(r, l, f32)) * ldf(a_attn, 64 + (l & 31), f32);
    #pragma unroll
    for (int off = 16; off; off >>= 1) v += __shfl_xor(v, off, 32);
    if ((l & 31) == 0) cvals[(t >> 6) * 2 + (l >> 5)] = v;
}

// ---------------- precompute: M = blockdiag(We@Wo) [32x32], c32 = rel@Wo [32] ----------------
__global__ void precompute_kernel(const void* __restrict__ We, const void* __restrict__ Wo,
                                  const void* __restrict__ rel, const int* __restrict__ flagp,
                                  float* __restrict__ M, float* __restrict__ c32)
{
    const int f32 = *flagp;
    int t = threadIdx.x;            // 1024 threads
    int m = t >> 5, j = t & 31;
    int h = m >> 4, c = m & 15;
    float s = 0.f;
    for (int jj = 0; jj < 32; ++jj)
        s += ldf(We, c * 64 + h * 32 + jj, f32) * ldf(Wo, (size_t)(h * 32 + jj) * 32 + j, f32);
    M[m * 32 + j] = s;
    if (t < 32) {
        float s2 = 0.f;
        for (int ch = 0; ch < 64; ++ch)
            s2 += ldf(rel, ch, f32) * ldf(Wo, (size_t)ch * 32 + t, f32);
        c32[t] = s2;
    }
}

// ---------------- edge scores: thread per 2 edges, rolled jb loop (no spills) ----------------
__global__ __launch_bounds__(256) void edge_score_kernel(
    const void* __restrict__ ea, const void* __restrict__ We,
    const int* __restrict__ row, const int* __restrict__ col,
    const float* __restrict__ sq_dst, const float* __restrict__ sk_src,
    const float* __restrict__ cvals, const void* __restrict__ a_attn,
    const int* __restrict__ flagp,
    float* __restrict__ ex_out, int num_e)
{
    const int f32 = *flagp;
    __shared__ float We_s[16 * 64];
    __shared__ float a3_s[32];
    __shared__ float c_s[2];
    for (int i = threadIdx.x; i < 16 * 64; i += 256) We_s[i] = ldf(We, i, f32);
    if (threadIdx.x < 32) a3_s[threadIdx.x] = ldf(a_attn, 96 + threadIdx.x, f32);
    if (threadIdx.x < 2)  c_s[threadIdx.x]  = cvals[threadIdx.x];
    __syncthreads();

    const int e0 = blockIdx.x * 512 + threadIdx.x;
    const int e1 = e0 + 256;
    const bool v1 = (e1 < num_e);
    if (e0 >= num_e) return;

    float er0[16], er1[16];
    load_ea16(ea, (size_t)e0, f32, er0);
    if (v1) load_ea16(ea, (size_t)e1, f32, er1);
    else {
        #pragma unroll
        for (int c = 0; c < 16; ++c) er1[c] = 0.f;
    }

    float acc00 = 0.f, acc01 = 0.f, acc10 = 0.f, acc11 = 0.f;
    #pragma unroll 1                       // keep rolled: avoids VGPR blowup/spills
    for (int jb = 0; jb < 64; jb += 16) {
        float t0[16], t1[16];
        #pragma unroll
        for (int jj = 0; jj < 16; ++jj) { t0[jj] = 0.f; t1[jj] = 0.f; }
        #pragma unroll
        for (int c = 0; c < 16; ++c) {
            #pragma unroll
            for (int jj = 0; jj < 16; ++jj) {
                float w = We_s[c * 64 + jb + jj];   // uniform broadcast
                t0[jj] += er0[c] * w;
                t1[jj] += er1[c] * w;
            }
        }
        float p0 = 0.f, p1 = 0.f;
        #pragma unroll
        for (int jj = 0; jj < 16; ++jj) {
            float a = a3_s[(jb + jj) & 31];
            p0 += fast_tanh(t0[jj]) * a;
            p1 += fast_tanh(t1[jj]) * a;
        }
        if (jb & 32) { acc01 += p0; acc11 += p1; }
        else         { acc00 += p0; acc10 += p1; }
    }

    {
        int d = col[e0], s = row[e0];
        float2 sqd = ((const float2*)sq_dst)[d];
        float2 sks = ((const float2*)sk_src)[s];
        float s0 = fminf(30.f, fmaxf(-30.f, acc00 + sqd.x + sks.x + c_s[0]));
        float s1 = fminf(30.f, fmaxf(-30.f, acc01 + sqd.y + sks.y + c_s[1]));
        ((float2*)ex_out)[e0] = make_float2(__expf(s0), __expf(s1));
    }
    if (v1) {
        int d = col[e1], s = row[e1];
        float2 sqd = ((const float2*)sq_dst)[d];
        float2 sks = ((const float2*)sk_src)[s];
        float s0 = fminf(30.f, fmaxf(-30.f, acc10 + sqd.x + sks.x + c_s[0]));
        float s1 = fminf(30.f, fmaxf(-30.f, acc11 + sqd.y + sks.y + c_s[1]));
        ((float2*)ex_out)[e1] = make_float2(__expf(s0), __expf(s1));
    }
}

// ---------------- CSR build ----------------
__global__ __launch_bounds__(256) void hist_kernel(const int* __restrict__ col,
                                                   int* __restrict__ cnt, int rb, int num_e)
{
    int e = blockIdx.x * 256 + threadIdx.x;
    if (e < num_e) atomicAdd(&cnt[rb + col[e]], 1);
}

__global__ __launch_bounds__(256) void scan1_kernel(const int* __restrict__ cnt,
                                                    int* __restrict__ partial, int n)
{
    __shared__ int wsum[4];
    int t = threadIdx.x;
    int i0 = blockIdx.x * 512 + 2 * t;
    int s = ((i0 < n) ? cnt[i0] : 0) + ((i0 + 1 < n) ? cnt[i0 + 1] : 0);
    #pragma unroll
    for (int o = 32; o; o >>= 1) s += __shfl_xor(s, o, 64);
    if ((t & 63) == 0) wsum[t >> 6] = s;
    __syncthreads();
    if (t == 0) partial[blockIdx.x] = wsum[0] + wsum[1] + wsum[2] + wsum[3];
}

__global__ void scan2_kernel(const int* __restrict__ partial, int* __restrict__ pp,
                             int* __restrict__ off, int nch, int noff)
{
    int lane = threadIdx.x;   // 64 threads
    int running = 0;
    for (int base = 0; base < nch; base += 64) {
        int i = base + lane;
        int o = (i < nch) ? partial[i] : 0;
        int v = o;
        #pragma unroll
        for (int d = 1; d < 64; d <<= 1) {
            int u = __shfl_up(v, d, 64);
            if (lane >= d) v += u;
        }
        if (i < nch) pp[i] = running + v - o;
        running += __shfl(v, 63, 64);
    }
    if (lane == 0) off[noff] = running;
}

__global__ __launch_bounds__(256) void scan3_kernel(const int* __restrict__ cnt,
                                                    const int* __restrict__ pp,
                                                    int* __restrict__ off,
                                                    int* __restrict__ cursor, int n)
{
    __shared__ int tmp[256];
    int t = threadIdx.x;
    int i0 = blockIdx.x * 512 + 2 * t;
    int v0 = (i0 < n) ? cnt[i0] : 0;
    int v1 = (i0 + 1 < n) ? cnt[i0 + 1] : 0;
    int pair = v0 + v1;
    tmp[t] = pair;
    __syncthreads();
    for (int d = 1; d < 256; d <<= 1) {
        int x = (t >= d) ? tmp[t - d] : 0;
        __syncthreads();
        tmp[t] += x;
        __syncthreads();
    }
    int excl = tmp[t] - pair + pp[blockIdx.x];
    if (i0 < n)     { off[i0] = excl;          cursor[i0] = excl; }
    if (i0 + 1 < n) { off[i0 + 1] = excl + v0; cursor[i0 + 1] = excl + v0; }
}

__global__ __launch_bounds__(256) void scatter_kernel(
    const int* __restrict__ row, const int* __restrict__ col,
    const float2* __restrict__ ex, int* __restrict__ cursor,
    uint4* __restrict__ payload, int rb, int num_e)
{
    int e = blockIdx.x * 256 + threadIdx.x;
    if (e >= num_e) return;
    int pos = atomicAdd(&cursor[rb + col[e]], 1);
    float2 x2 = ex[e];
    payload[pos] = make_uint4((unsigned)row[e], __float_as_uint(x2.x),
                              __float_as_uint(x2.y), (unsigned)e);
}

// ---------------- fused aggregation + output projection (CSR, no atomics) ----------------
__global__ __launch_bounds__(256) void agg_final_kernel(
    const uint4* __restrict__ payload, const int* __restrict__ off,
    const float* __restrict__ v_src, const void* __restrict__ x,
    const void* __restrict__ ea, const void* __restrict__ Wo,
    const void* __restrict__ bo, const void* __restrict__ Wr,
    const float* __restrict__ M, const float* __restrict__ c32,
    const int* __restrict__ flagp, void* __restrict__ out,
    size_t out_elem_off, int relbase, int n_nodes)
{
    const int f32  = *flagp;
    const int lane = threadIdx.x & 63;
    const int wv   = threadIdx.x >> 6;
    const int j    = lane & 31;
    const int half = lane >> 5;

    __shared__ float stage[4][160];   // per-wave: y[64] | x[64] | u[32]

    float WoR[32], WrR[32], MR[16];
    const int cb = half * 32;
    #pragma unroll
    for (int cc = 0; cc < 32; ++cc) {
        WoR[cc] = ldf(Wo, (size_t)(cb + cc) * 32 + j, f32);
        WrR[cc] = ldf(Wr, (size_t)(cb + cc) * 32 + j, f32);
    }
    const int ub = half * 16;
    #pragma unroll
    for (int cc = 0; cc < 16; ++cc) MR[cc] = M[(ub + cc) * 32 + j];
    const float boR  = ldf(bo, j, f32);
    const float c32R = c32[j];

    const int stride = gridDim.x * 4;
    const int iters  = (n_nodes + stride - 1) / stride;
    int d = blockIdx.x * 4 + wv;

    for (int it = 0; it < iters; ++it, d += stride) {
        const bool valid = (d < n_nodes);
        const int dd  = valid ? d : (n_nodes - 1);
        const int idx = relbase + dd;
        const int b   = __builtin_amdgcn_readfirstlane(off[idx]);
        const int en  = __builtin_amdgcn_readfirstlane(off[idx + 1]);
        const int deg = en - b;

        float den0 = 0.f, den1 = 0.f;
        #pragma unroll 4
        for (int k = b; k < en; ++k) {
            uint4 p = payload[k];
            den0 += __uint_as_float(p.y);
            den1 += __uint_as_float(p.z);
        }
        float inv0 = (deg > 0) ? __builtin_amdgcn_rcpf(den0) : 0.f;
        float inv1 = (deg > 0) ? __builtin_amdgcn_rcpf(den1) : 0.f;
        const float invh = (lane < 32) ? inv0 : inv1;

        float y = 0.f, uacc = 0.f;
        const int c16 = lane & 15;
        #pragma unroll 2
        for (int k = b; k < en; ++k) {
            uint4 p = payload[k];
            float exh = (lane < 32) ? __uint_as_float(p.y) : __uint_as_float(p.z);
            float w = exh * invh;
            float vv = v_src[(size_t)p.x * 64 + lane];
            y = fmaf(w, vv, y);
            float eav = ldf(ea, (size_t)p.w * 16 + c16, f32);
            uacc = fmaf(w, eav, uacc);
        }

        float xv = ldf(x, (size_t)dd * 64 + lane, f32);

        float* st = stage[wv];
        st[lane] = y;
        st[64 + lane] = xv;
        if ((lane & 31) < 16) st[128 + half * 16 + c16] = uacc;
        __syncthreads();

        float acc = 0.f;
        #pragma unroll
        for (int cc = 0; cc < 32; ++cc) {
            acc = fmaf(st[cb + cc], WoR[cc], acc);
            acc = fmaf(st[64 + cb + cc], WrR[cc], acc);
        }
        #pragma unroll
        for (int cc = 0; cc < 16; ++cc)
            acc = fmaf(st[128 + ub + cc], MR[cc], acc);

        float other = __shfl(acc, lane ^ 32, 64);
        if (valid && lane < 32) {
            float o = acc + other + boR + ((deg > 0) ? c32R : 0.f);
            stf(out, out_elem_off + (size_t)dd * 32 + j, f32, o);
        }
        __syncthreads();
    }
}

extern "C" void kernel_launch(void* const* d_in, const int* in_sizes, int n_in,
                              void* d_out, int out_size, void* d_ws, size_t ws_size,
                              hipStream_t stream)
{
    const void* x_a   = d_in[0];
    const void* x_b   = d_in[1];
    const void* ea1   = d_in[2];
    const void* ea2   = d_in[3];
    const void* Wq_a  = d_in[4];
    const void* Wk_a  = d_in[5];
    const void* Wv_a  = d_in[6];
    const void* Wq_b  = d_in[7];
    const void* Wk_b  = d_in[8];
    const void* Wv_b  = d_in[9];
    const void* emb_a = d_in[10];
    const void* emb_b = d_in[11];
    const void* rel1  = d_in[12];
    const void* rel2  = d_in[13];
    const void* We    = d_in[14];
    const void* a_at  = d_in[15];
    const void* Wo_a  = d_in[16];
    const void* bo_a  = d_in[17];
    const void* Wo_b  = d_in[18];
    const void* bo_b  = d_in[19];
    const void* Wr_a  = d_in[20];
    const void* Wr_b  = d_in[21];
    const int*  row1  = (const int*)d_in[22];
    const int*  col1  = (const int*)d_in[23];
    const int*  row2  = (const int*)d_in[24];
    const int*  col2  = (const int*)d_in[25];

    const int N = in_sizes[0] / 64;   // nodes per type
    const int E = in_sizes[22];       // edges per relation

    // ---- workspace layout ----
    float* ws = (float*)d_ws;
    size_t off = 0;
    int*   flag = (int*)ws;        off += 64;
    float* v_a  = ws + off;        off += (size_t)N * 64;
    float* v_b  = ws + off;        off += (size_t)N * 64;
    float* sq_a = ws + off;        off += (size_t)N * 2;
    float* sk_a = ws + off;        off += (size_t)N * 2;
    float* sq_b = ws + off;        off += (size_t)N * 2;
    float* sk_b = ws + off;        off += (size_t)N * 2;
    float* cvals = ws + off;       off += 4;
    off = (off + 3) & ~(size_t)3;  // 16B align
    unsigned short* wt = (unsigned short*)(ws + off); off += 6 * 4096 / 2;  // 6 transposed 64x64 bf16
    off = (off + 3) & ~(size_t)3;  // 16B align
    unsigned short* xc = (unsigned short*)(ws + off); off += (size_t)2 * N * 64 / 2;  // bf16 x, both types
    float* ex1  = ws + off;        off += (size_t)E * 2;
    float* ex2  = ws + off;        off += (size_t)E * 2;
    float* M1   = ws + off;        off += 1024;
    float* c321 = ws + off;        off += 32;
    float* M2   = ws + off;        off += 1024;
    float* c322 = ws + off;        off += 32;
    int*   cnt    = (int*)(ws + off);  off += (size_t)2 * N;
    int*   offs   = (int*)(ws + off);  off += (size_t)2 * N + 2;
    int*   cursor = (int*)(ws + off);  off += (size_t)2 * N;
    int*   partial = (int*)(ws + off); off += 512;
    int*   pp      = (int*)(ws + off); off += 512;
    off = (off + 3) & ~(size_t)3;     // 16B align for uint4
    uint4* payload = (uint4*)(ws + off); off += (size_t)2 * E * 4;

    const int tiles        = (N + 15) >> 4;
    const int mfma_blocks  = (2 * tiles + 3) / 4;       // one tile per wave, both types
    const int conv_blocks  = (int)(((size_t)2 * N * 64 / 8 + 255) / 256);
    const int score_blocks = (E + 511) / 512;
    const int eb_blocks    = (E + 255) / 256;
    const int nch          = (2 * N + 511) / 512;
    const int agg_blocks   = 2048;

    detect_kernel<<<1, 128, 0, stream>>>((const unsigned short*)a_at, flag);
    hipMemsetAsync(cnt, 0, (size_t)2 * N * sizeof(int), stream);

    convert_x_kernel<<<conv_blocks, 256, 0, stream>>>(x_a, x_b, flag, xc, (size_t)N * 64);
    transpose_w_kernel<<<6, 256, 0, stream>>>(Wq_a, Wk_a, Wv_a, Wq_b, Wk_b, Wv_b, flag, wt);
    node_prep_mfma_kernel<<<mfma_blocks, 256, 0, stream>>>(
        xc, wt, emb_a, emb_b, a_at, flag,
        v_a, v_b, sq_a, sk_a, sq_b, sk_b, N, tiles);

    rel_const_kernel<<<1, 128, 0, stream>>>(rel1, rel2, a_at, flag, cvals);
    precompute_kernel<<<1, 1024, 0, stream>>>(We, Wo_b, rel1, flag, M1, c321);  // rel1 -> out_b
    precompute_kernel<<<1, 1024, 0, stream>>>(We, Wo_a, rel2, flag, M2, c322);  // rel2 -> out_a

    hist_kernel<<<eb_blocks, 256, 0, stream>>>(col1, cnt, 0, E);
    hist_kernel<<<eb_blocks, 256, 0, stream>>>(col2, cnt, N, E);
    scan1_kernel<<<nch, 256, 0, stream>>>(cnt, partial, 2 * N);
    scan2_kernel<<<1, 64, 0, stream>>>(partial, pp, offs, nch, 2 * N);
    scan3_kernel<<<nch, 256, 0, stream>>>(cnt, pp, offs, cursor, 2 * N);

    edge_score_kernel<<<score_blocks, 256, 0, stream>>>(ea1, We, row1, col1, sq_b, sk_a, cvals + 0, a_at, flag, ex1, E);
    edge_score_kernel<<<score_blocks, 256, 0, stream>>>(ea2, We, row2, col2, sq_a, sk_b, cvals + 2, a_at, flag, ex2, E);

    scatter_kernel<<<eb_blocks, 256, 0, stream>>>(row1, col1, (const float2*)ex1, cursor, payload, 0, E);
    scatter_kernel<<<eb_blocks, 256, 0, stream>>>(row2, col2, (const float2*)ex2, cursor, payload, N, E);

    // rel1: src a -> dst b (out_b at element offset N*32); rel2: src b -> dst a
    agg_final_kernel<<<agg_blocks, 256, 0, stream>>>(payload, offs, v_a, x_b, ea1, Wo_b, bo_b, Wr_b,
                                                     M1, c321, flag, d_out, (size_t)N * 32, 0, N);
    agg_final_kernel<<<agg_blocks, 256, 0, stream>>>(payload, offs, v_b, x_a, ea2, Wo_a, bo_a, Wr_a,
                                                     M2, c322, flag, d_out, 0, N, N);
}